// Round 8
// baseline (137.506 us; speedup 1.0000x reference)
//
#include <hip/hip_runtime.h>
#include <hip/hip_bf16.h>
#include <math.h>

#define NHEADS 8
#define NTOK   1024
#define MTOK   2048

typedef __attribute__((ext_vector_type(8))) short  sh8;
typedef __attribute__((ext_vector_type(8))) __bf16 bf16x8;
typedef __attribute__((ext_vector_type(4))) float  f32x4;

__device__ __forceinline__ short f2bf(float v) {
    return __builtin_bit_cast(short, __float2bfloat16(v));
}
__device__ __forceinline__ float bf2f(short v) {
    return __builtin_bit_cast(float, ((unsigned)(unsigned short)v) << 16);
}
__device__ __forceinline__ float ex2(float v) {
    return __builtin_amdgcn_exp2f(v);
}
__device__ __forceinline__ f32x4 mfma16(sh8 a, sh8 b, f32x4 c) {
    return __builtin_amdgcn_mfma_f32_16x16x32_bf16(
        __builtin_bit_cast(bf16x8, a), __builtin_bit_cast(bf16x8, b), c, 0, 0, 0);
}
__device__ __forceinline__ void aload16(void* lds, const void* g) {
    __builtin_amdgcn_global_load_lds(
        (const __attribute__((address_space(1))) unsigned int*)g,
        (__attribute__((address_space(3))) unsigned int*)lds, 16, 0, 0);
}

#define LOG2E 1.4426950408889634f

// ---------------- LayerNorm -> bf16 ----------------
__global__ __launch_bounds__(256) void ln_bf16(const float* __restrict__ x,
    const float* __restrict__ g, const float* __restrict__ bta, short* __restrict__ y)
{
    int row = blockIdx.x, t = threadIdx.x;
    const float* xr = x + (size_t)row * 512;
    float2 v = *reinterpret_cast<const float2*>(&xr[t*2]);
    float s = v.x + v.y, ss = v.x*v.x + v.y*v.y;
    #pragma unroll
    for (int m = 1; m < 64; m <<= 1) { s += __shfl_xor(s, m); ss += __shfl_xor(ss, m); }
    __shared__ float red[8];
    int wid = t >> 6, lane = t & 63;
    if (!lane) { red[wid] = s; red[4+wid] = ss; }
    __syncthreads();
    s = red[0]+red[1]+red[2]+red[3]; ss = red[4]+red[5]+red[6]+red[7];
    float mu = s*(1.f/512), var = ss*(1.f/512) - mu*mu, rs = rsqrtf(var + 1e-5f);
    float2 gg = *reinterpret_cast<const float2*>(&g[t*2]);
    float2 bb = *reinterpret_cast<const float2*>(&bta[t*2]);
    short2 o; o.x = f2bf((v.x-mu)*rs*gg.x + bb.x); o.y = f2bf((v.y-mu)*rs*gg.y + bb.y);
    *reinterpret_cast<short2*>(&y[(size_t)row*512 + t*2]) = o;
}

// ---------------- fp32 W[K][N] -> bf16 W^T[N][K] ----------------
__global__ __launch_bounds__(256) void wconv_t(const float* __restrict__ W,
    short* __restrict__ WT, int K, int N)
{
    __shared__ float t[32][33];
    int bn = blockIdx.x * 32, bk = blockIdx.y * 32;
    int c = threadIdx.x & 31, r8 = threadIdx.x >> 5;
    #pragma unroll
    for (int i = 0; i < 4; ++i) {
        int r = r8 + i*8;
        t[r][c] = W[(size_t)(bk + r)*N + bn + c];
    }
    __syncthreads();
    #pragma unroll
    for (int i = 0; i < 4; ++i) {
        int r = r8 + i*8;
        WT[(size_t)(bn + r)*K + bk + c] = f2bf(t[c][r]);
    }
}

// ---------------- o[i] = a[i] + bias[i % 512]  (f32, vectorized) ----------------
__global__ __launch_bounds__(256) void addbias_f32(const float* __restrict__ a,
    const float* __restrict__ bias, float* __restrict__ o)
{
    int e = (blockIdx.x*256 + threadIdx.x)*4;
    float4 av = *reinterpret_cast<const float4*>(a + e);
    float4 bv = *reinterpret_cast<const float4*>(bias + (e & 511));
    float4 ov = {av.x+bv.x, av.y+bv.y, av.z+bv.z, av.w+bv.w};
    *reinterpret_cast<float4*>(o + e) = ov;
}

// ---------------- pack padding mask into per-(row, 64-tile) bit masks ----------
__global__ __launch_bounds__(256) void mask_pack(const unsigned char* __restrict__ m,
    unsigned long long* __restrict__ mb)
{
    int gw = blockIdx.x*4 + (threadIdx.x >> 6);   // 32768 waves
    int row = gw >> 4, jt = gw & 15, j = threadIdx.x & 63;
    unsigned char v = m[(size_t)row*NTOK + jt*64 + j];
    unsigned long long bits = __ballot(v != 0);
    if (j == 0) mb[(size_t)row*16 + jt] = bits;
}

// ---------------- rnT[b*1024+j][i] = |c[b,i]-c[b,j]| as bf16 (head-independent) --
__global__ __launch_bounds__(256) void rn_pre(const float* __restrict__ coords,
    short* __restrict__ rnT)
{
    int row = blockIdx.x;                    // b*1024 + j
    int b = row >> 10;
    float2 cj = *reinterpret_cast<const float2*>(&coords[(size_t)row*2]);
    int i0 = threadIdx.x * 4;
    float4 a = *reinterpret_cast<const float4*>(&coords[(size_t)(b*1024 + i0)*2]);
    float4 d = *reinterpret_cast<const float4*>(&coords[(size_t)(b*1024 + i0 + 2)*2]);
    short4 o;
    o.x = f2bf(sqrtf((a.x-cj.x)*(a.x-cj.x) + (a.y-cj.y)*(a.y-cj.y)));
    o.y = f2bf(sqrtf((a.z-cj.x)*(a.z-cj.x) + (a.w-cj.y)*(a.w-cj.y)));
    o.z = f2bf(sqrtf((d.x-cj.x)*(d.x-cj.x) + (d.y-cj.y)*(d.y-cj.y)));
    o.w = f2bf(sqrtf((d.z-cj.x)*(d.z-cj.x) + (d.w-cj.y)*(d.w-cj.y)));
    *reinterpret_cast<short4*>(&rnT[(size_t)row*1024 + i0]) = o;
}

// ---------------- bf16 MFMA GEMM, 64x64 tile, BK=64, 3-stage counted-vmcnt ----
// QSC: fold attention scale AND log2(e) into q columns (cols < 512)
template<int EPI, bool OUTBF, bool BIAS_ROW, int SPLITK, bool QSC, int NT>
__global__ __launch_bounds__(256) void gemm64(
    const short* __restrict__ A, const short* __restrict__ BT,
    const float* __restrict__ bias, void* __restrict__ Cout,
    int M, int N, int K, int nbx)
{
    __shared__ sh8 As8[3][512];
    __shared__ sh8 Bs8[3][512];
    int tid = threadIdx.x;
    int w = tid >> 6, lane = tid & 63, lr = lane & 15, lg = lane >> 4;
    int wr = w >> 1, wc = w & 1;
    int cpx = gridDim.x >> 3;
    int swz = (blockIdx.x & 7)*cpx + (blockIdx.x >> 3);
    int bx = swz % nbx, by = swz / nbx;
    int bm0 = by*64, bn0 = bx*64;
    int kbeg = (K / SPLITK) * blockIdx.z;

    f32x4 zero = {0.f,0.f,0.f,0.f};
    f32x4 acc[2][2];
    #pragma unroll
    for (int m = 0; m < 2; ++m)
        #pragma unroll
        for (int n = 0; n < 2; ++n) acc[m][n] = zero;

    #define STAGE(buf, k0) { \
        _Pragma("unroll") \
        for (int it = 0; it < 2; ++it) { \
            int s = tid + it*256; \
            int r = s >> 3, g = s & 7; \
            int ksw = (k0) + ((g ^ (r & 7)) << 3); \
            aload16(&As8[buf][s], A  + (size_t)(bm0 + r)*K + ksw); \
            aload16(&Bs8[buf][s], BT + (size_t)(bn0 + r)*K + ksw); \
        } }

    STAGE(0, kbeg)
    if (NT > 1) STAGE(1, kbeg + 64)

    #pragma unroll
    for (int t = 0; t < NT; ++t) {
        if (t + 1 < NT) asm volatile("s_waitcnt vmcnt(4)" ::: "memory");
        else            asm volatile("s_waitcnt vmcnt(0)" ::: "memory");
        __syncthreads();
        int buf = t % 3;
        sh8 af[2][2], bfv[2][2];
        #pragma unroll
        for (int m = 0; m < 2; ++m) {
            int R = wr*32 + m*16 + lr;
            #pragma unroll
            for (int s = 0; s < 2; ++s) af[m][s] = As8[buf][R*8 + ((s*4+lg) ^ (R & 7))];
        }
        #pragma unroll
        for (int n = 0; n < 2; ++n) {
            int R = wc*32 + n*16 + lr;
            #pragma unroll
            for (int s = 0; s < 2; ++s) bfv[n][s] = Bs8[buf][R*8 + ((s*4+lg) ^ (R & 7))];
        }
        if (t + 2 < NT) STAGE((t+2)%3, kbeg + (t+2)*64)
        #pragma unroll
        for (int m = 0; m < 2; ++m)
            #pragma unroll
            for (int n = 0; n < 2; ++n)
                #pragma unroll
                for (int s = 0; s < 2; ++s)
                    acc[m][n] = mfma16(af[m][s], bfv[n][s], acc[m][n]);
        asm volatile("s_waitcnt lgkmcnt(0)" ::: "memory");
    }
    #undef STAGE

    #pragma unroll
    for (int m = 0; m < 2; ++m) {
        #pragma unroll
        for (int n = 0; n < 2; ++n) {
            #pragma unroll
            for (int r = 0; r < 4; ++r) {
                int row = bm0 + wr*32 + m*16 + lg*4 + r;
                int col = bn0 + wc*32 + n*16 + lr;
                if (EPI == 3) {
                    atomicAdd((float*)Cout + (size_t)row*N + col, acc[m][n][r]);
                } else {
                    float v = acc[m][n][r] + (BIAS_ROW ? bias[row] : bias[col]);
                    if (QSC && col < 512) v *= (0.125f * LOG2E);
                    if (EPI == 2) v = 0.5f * v * (1.0f + erff(v * 0.70710678f));
                    if (OUTBF) ((short*)Cout)[(size_t)row*N + col] = f2bf(v);
                    else       ((float*)Cout)[(size_t)row*N + col] = v;
                }
            }
        }
    }
}

// ---------------- barrier-free register-KV flash attention, KV-split x2 -------
// dbuf register prefetch; amdgpu_waves_per_eu(2,2) pins occupancy we actually
// launch (2048 waves = 2/SIMD) -> full 256-VGPR budget, no spill.
// Softmax in log2 domain (q pre-scaled by 0.125*log2e).
__global__ __launch_bounds__(256) __attribute__((amdgpu_waves_per_eu(2, 2)))
void attn_reg(
    const short* __restrict__ qk, const short* __restrict__ vt,
    const short* __restrict__ rnT, const unsigned long long* __restrict__ mb64,
    const float* __restrict__ w_edge, short* __restrict__ Op, float* __restrict__ ml)
{
    __shared__ sh8 Ps8[4][128];   // per-wave P tile [16 q][64 k], swizzled

    int swz = (blockIdx.x & 7)*64 + (blockIdx.x >> 3);   // 512 blocks, bijective
    int w = threadIdx.x >> 6, lane = threadIdx.x & 63;
    int lr = lane & 15, lg = lane >> 4;
    int gw = swz*4 + w;        // 2048 waves
    int qt = gw & 63;
    int h  = (gw >> 6) & 7;
    int b  = (gw >> 9) & 1;
    int ks = gw >> 10;         // KV split 0/1

    const int qrow0 = b*NTOK + qt*16;

    sh8 qf[2];
    #pragma unroll
    for (int s = 0; s < 2; ++s)
        qf[s] = *reinterpret_cast<const sh8*>(qk + (size_t)(qrow0 + lr)*1024 + h*64 + s*32 + lg*8);

    float we2l = w_edge[2*NHEADS + h] * LOG2E;

    float m_i[4], l_lane[4];
    f32x4 zero = {0.f,0.f,0.f,0.f};
    f32x4 accO[4];
    #pragma unroll
    for (int r = 0; r < 4; ++r) { m_i[r] = -1e30f; l_lane[r] = 0.f; }
    #pragma unroll
    for (int n = 0; n < 4; ++n) accO[n] = zero;

    const short* kb = qk + 512 + h*64;
    const short* vb = vt + (size_t)h*64*2048 + b*NTOK;

    // double-buffered K/V register fragments
    sh8 kf0[2][4], kf1[2][4], vf0[2][4], vf1[2][4];

    #define LOADT(bf, jt) { \
        int k0_ = b*NTOK + (jt)*64; \
        _Pragma("unroll") \
        for (int n = 0; n < 4; ++n) { \
            const short* kr = kb + (size_t)(k0_ + n*16 + lr)*1024 + lg*8; \
            kf0[bf][n] = *reinterpret_cast<const sh8*>(kr); \
            kf1[bf][n] = *reinterpret_cast<const sh8*>(kr + 32); \
            const short* vr = vb + (size_t)(n*16 + lr)*2048 + (jt)*64 + lg*8; \
            vf0[bf][n] = *reinterpret_cast<const sh8*>(vr); \
            vf1[bf][n] = *reinterpret_cast<const sh8*>(vr + 32); \
        } }

    LOADT(0, ks*8)

    #pragma unroll
    for (int t = 0; t < 8; ++t) {
        int buf = t & 1;
        int jt = ks*8 + t;

        // prefetch next tile's K/V into the other buffer (hides under this tile)
        if (t < 7) LOADT(buf ^ 1, jt + 1)

        // radial-norm (precomputed, transposed: 4 bf16 per 8B load) + mask bits
        short4 rnp[4];
        #pragma unroll
        for (int n = 0; n < 4; ++n)
            rnp[n] = *reinterpret_cast<const short4*>(
                &rnT[(size_t)(b*1024 + jt*64 + n*16 + lr)*1024 + qt*16 + lg*4]);
        unsigned long long mrow[4];
        #pragma unroll
        for (int r = 0; r < 4; ++r)
            mrow[r] = mb64[(size_t)(qrow0 + lg*4 + r)*16 + jt];

        // S = Q K^T (q pre-scaled by 0.125*log2e)
        f32x4 Sv[4];
        #pragma unroll
        for (int n = 0; n < 4; ++n)
            Sv[n] = mfma16(qf[1], kf1[buf][n], mfma16(qf[0], kf0[buf][n], zero));

        // radial bias + mask (log2 domain)
        #pragma unroll
        for (int n = 0; n < 4; ++n) {
            #pragma unroll
            for (int r = 0; r < 4; ++r) {
                short rnb = (r == 0) ? rnp[n].x : (r == 1) ? rnp[n].y
                          : (r == 2) ? rnp[n].z : rnp[n].w;
                float sv = fmaf(bf2f(rnb), we2l, Sv[n][r]);
                Sv[n][r] = ((mrow[r] >> (n*16 + lr)) & 1ull) ? -1e9f : sv;
            }
        }

        // online softmax (row = 16 lanes sharing lg); lane-local l
        #pragma unroll
        for (int r = 0; r < 4; ++r) {
            float mx = fmaxf(fmaxf(Sv[0][r], Sv[1][r]), fmaxf(Sv[2][r], Sv[3][r]));
            #pragma unroll
            for (int msk = 1; msk < 16; msk <<= 1) mx = fmaxf(mx, __shfl_xor(mx, msk));
            float mnew = fmaxf(m_i[r], mx);
            float f = ex2(m_i[r] - mnew);
            m_i[r] = mnew;
            float rs = 0.f;
            #pragma unroll
            for (int n = 0; n < 4; ++n) { float p = ex2(Sv[n][r] - mnew); Sv[n][r] = p; rs += p; }
            l_lane[r] = l_lane[r]*f + rs;
            #pragma unroll
            for (int n = 0; n < 4; ++n) accO[n][r] *= f;
        }

        // P -> wave-private LDS (swizzled), reload as A fragments
        short* Pw = (short*)&Ps8[w][0];
        #pragma unroll
        for (int r = 0; r < 4; ++r) {
            int q = lg*4 + r;
            #pragma unroll
            for (int n = 0; n < 4; ++n) {
                int k = n*16 + lr;
                Pw[q*64 + (((k>>3) ^ (q&7)) << 3) + (k&7)] = f2bf(Sv[n][r]);
            }
        }
        sh8 pa[2];
        #pragma unroll
        for (int s = 0; s < 2; ++s)
            pa[s] = Ps8[w][lr*8 + ((s*4 + lg) ^ (lr & 7))];

        // PV
        #pragma unroll
        for (int n = 0; n < 4; ++n)
            accO[n] = mfma16(pa[1], vf1[buf][n], mfma16(pa[0], vf0[buf][n], accO[n]));
    }
    #undef LOADT

    // reduce l once
    #pragma unroll
    for (int r = 0; r < 4; ++r) {
        float ls = l_lane[r];
        #pragma unroll
        for (int msk = 1; msk < 16; msk <<= 1) ls += __shfl_xor(ls, msk);
        l_lane[r] = ls;
    }

    // partials: unnormalized bf16 O + (m, l)
    #pragma unroll
    for (int r = 0; r < 4; ++r) {
        size_t row = (size_t)(ks*MTOK + qrow0 + lg*4 + r);
        #pragma unroll
        for (int n = 0; n < 4; ++n)
            Op[row*512 + h*64 + n*16 + lr] = f2bf(accO[n][r]);
        if (lr == 0) {
            ml[(row*NHEADS + h)*2 + 0] = m_i[r];
            ml[(row*NHEADS + h)*2 + 1] = l_lane[r];
        }
    }
}

// ---------------- combine 2 KV-split partials -> bf16 O (log2-domain m) -------
__global__ __launch_bounds__(256) void attn_combine(const short* __restrict__ Op,
    const float* __restrict__ ml, short* __restrict__ ob)
{
    int idx = blockIdx.x*256 + threadIdx.x;     // MTOK*128 threads
    int tok = idx >> 7, dd = (idx & 127) * 4;
    int h = dd >> 6;
    float m0 = ml[((size_t)tok*NHEADS + h)*2 + 0];
    float l0 = ml[((size_t)tok*NHEADS + h)*2 + 1];
    float m1 = ml[(((size_t)MTOK + tok)*NHEADS + h)*2 + 0];
    float l1 = ml[(((size_t)MTOK + tok)*NHEADS + h)*2 + 1];
    float mm = fmaxf(m0, m1);
    float w0 = ex2(m0 - mm), w1 = ex2(m1 - mm);
    float inv = 1.f / (w0*l0 + w1*l1);
    short4 a = *reinterpret_cast<const short4*>(&Op[(size_t)tok*512 + dd]);
    short4 c = *reinterpret_cast<const short4*>(&Op[((size_t)MTOK + tok)*512 + dd]);
    short4 o;
    o.x = f2bf((bf2f(a.x)*w0 + bf2f(c.x)*w1)*inv);
    o.y = f2bf((bf2f(a.y)*w0 + bf2f(c.y)*w1)*inv);
    o.z = f2bf((bf2f(a.z)*w0 + bf2f(c.z)*w1)*inv);
    o.w = f2bf((bf2f(a.w)*w0 + bf2f(c.w)*w1)*inv);
    *reinterpret_cast<short4*>(&ob[(size_t)tok*512 + dd]) = o;
}

// -------------------------------------------------------------------------------
extern "C" void kernel_launch(void* const* d_in, const int* in_sizes, int n_in,
                              void* d_out, int out_size, void* d_ws, size_t ws_size,
                              hipStream_t stream)
{
    const float* x      = (const float*)d_in[0];
    const float* coords = (const float*)d_in[1];
    const unsigned char* mask = (const unsigned char*)d_in[2];
    const float* ln1_g = (const float*)d_in[3];
    const float* ln1_b = (const float*)d_in[4];
    const float* w_qkv = (const float*)d_in[5];
    const float* b_qkv = (const float*)d_in[6];
    const float* w_edge= (const float*)d_in[7];
    const float* w_out = (const float*)d_in[8];
    const float* b_out = (const float*)d_in[9];
    const float* ln2_g = (const float*)d_in[10];
    const float* ln2_b = (const float*)d_in[11];
    const float* w1    = (const float*)d_in[12];
    const float* b1    = (const float*)d_in[13];
    const float* w2    = (const float*)d_in[14];
    const float* b2    = (const float*)d_in[15];
    float* out = (float*)d_out;

    char* W = (char*)d_ws;
    const size_t MB = 1024*1024;
    float* x1    = (float*)(W);                    // [0,4M) f32
    short* qk    = (short*)(W + 4*MB);             // [4M,8M)
    short* vtb   = (short*)(W + 8*MB);             // [8M,10M)
    short* woutT = (short*)(W + 10*MB);            // [10M,10.5M)
    short* xln   = (short*)(W + 10*MB + 512*1024); // [10.5M,12.5M)  (later y)
    short* wqkvT = (short*)(W + 12*MB + 512*1024); // [12.5M,14M)
    short* Opart = (short*)(W + 14*MB + 512*1024); // [14.5M,18.5M) bf16 2x2048x512
    short* rnT   = (short*)(W + 18*MB + 512*1024); // [18.5M,22.5M) bf16 2048x1024
    float* mlp   = (float*)(W + 22*MB + 512*1024); // [22.5M,22.75M)
    unsigned long long* mb64 = (unsigned long long*)(W + 23*MB); // [23M,23.25M)
    short* ob    = (short*)(W + 6*MB);             // [6M,8M)  (qk dead after attn)
    short* y     = xln;
    short* w1T   = (short*)(W + 4*MB);             // [4M,6M)  (qk dead)
    short* w2T   = (short*)(W + 8*MB);             // [8M,10M) (vtb dead)
    short* hid   = (short*)(W + 14*MB + 512*1024); // [14.5M,22.5M) (Opart/rnT dead)

    // ---- phase 1 ----
    mask_pack<<<dim3(8192,1,1), 256, 0, stream>>>(mask, mb64);
    rn_pre<<<dim3(2048,1,1), 256, 0, stream>>>(coords, rnT);
    wconv_t<<<dim3(1536/32, 512/32), 256, 0, stream>>>(w_qkv, wqkvT, 512, 1536);
    wconv_t<<<dim3(512/32, 512/32), 256, 0, stream>>>(w_out, woutT, 512, 512);
    ln_bf16<<<MTOK, 256, 0, stream>>>(x, ln1_g, ln1_b, xln);
    gemm64<0,true,false,1,true,8><<<dim3(512,1,1), 256, 0, stream>>>(
        xln, wqkvT, b_qkv, qk, MTOK, 1024, 512, 16);
    gemm64<0,true,true,1,false,8><<<dim3(256,1,1), 256, 0, stream>>>(
        wqkvT + (size_t)1024*512, xln, b_qkv + 1024, vtb, 512, MTOK, 512, 32);
    attn_reg<<<dim3(512,1,1), 256, 0, stream>>>(qk, vtb, rnT, mb64, w_edge, Opart, mlp);
    attn_combine<<<dim3(1024,1,1), 256, 0, stream>>>(Opart, mlp, ob);
    addbias_f32<<<1024, 256, 0, stream>>>(x, b_out, x1);
    gemm64<3,false,false,2,false,4><<<dim3(256,1,2), 256, 0, stream>>>(
        ob, woutT, nullptr, x1, MTOK, 512, 512, 8);
    // ---- phase 2 ----
    wconv_t<<<dim3(2048/32, 512/32), 256, 0, stream>>>(w1, w1T, 512, 2048);
    wconv_t<<<dim3(512/32, 2048/32), 256, 0, stream>>>(w2, w2T, 2048, 512);
    ln_bf16<<<MTOK, 256, 0, stream>>>(x1, ln2_g, ln2_b, y);
    gemm64<2,true,false,1,false,8><<<dim3(1024,1,1), 256, 0, stream>>>(
        y, w1T, b1, hid, MTOK, 2048, 512, 32);
    addbias_f32<<<1024, 256, 0, stream>>>(x1, b2, out);
    gemm64<3,false,false,4,false,8><<<dim3(256,1,4), 256, 0, stream>>>(
        hid, w2T, nullptr, out, MTOK, 512, 2048, 8);
}

// Round 9
// 114.415 us; speedup vs baseline: 1.2018x; 1.2018x over previous
//
#include <hip/hip_runtime.h>
#include <hip/hip_bf16.h>
#include <math.h>

#define NHEADS 8
#define NTOK   1024
#define MTOK   2048

typedef __attribute__((ext_vector_type(8))) short  sh8;
typedef __attribute__((ext_vector_type(8))) __bf16 bf16x8;
typedef __attribute__((ext_vector_type(4))) float  f32x4;

__device__ __forceinline__ short f2bf(float v) {
    return __builtin_bit_cast(short, __float2bfloat16(v));
}
__device__ __forceinline__ float bf2f(short v) {
    return __builtin_bit_cast(float, ((unsigned)(unsigned short)v) << 16);
}
__device__ __forceinline__ float ex2(float v) {
    return __builtin_amdgcn_exp2f(v);
}
__device__ __forceinline__ f32x4 mfma16(sh8 a, sh8 b, f32x4 c) {
    return __builtin_amdgcn_mfma_f32_16x16x32_bf16(
        __builtin_bit_cast(bf16x8, a), __builtin_bit_cast(bf16x8, b), c, 0, 0, 0);
}
__device__ __forceinline__ void aload16(void* lds, const void* g) {
    __builtin_amdgcn_global_load_lds(
        (const __attribute__((address_space(1))) unsigned int*)g,
        (__attribute__((address_space(3))) unsigned int*)lds, 16, 0, 0);
}

#define LOG2E 1.4426950408889634f

// ---------------- LayerNorm -> bf16 ----------------
__global__ __launch_bounds__(256) void ln_bf16(const float* __restrict__ x,
    const float* __restrict__ g, const float* __restrict__ bta, short* __restrict__ y)
{
    int row = blockIdx.x, t = threadIdx.x;
    const float* xr = x + (size_t)row * 512;
    float2 v = *reinterpret_cast<const float2*>(&xr[t*2]);
    float s = v.x + v.y, ss = v.x*v.x + v.y*v.y;
    #pragma unroll
    for (int m = 1; m < 64; m <<= 1) { s += __shfl_xor(s, m); ss += __shfl_xor(ss, m); }
    __shared__ float red[8];
    int wid = t >> 6, lane = t & 63;
    if (!lane) { red[wid] = s; red[4+wid] = ss; }
    __syncthreads();
    s = red[0]+red[1]+red[2]+red[3]; ss = red[4]+red[5]+red[6]+red[7];
    float mu = s*(1.f/512), var = ss*(1.f/512) - mu*mu, rs = rsqrtf(var + 1e-5f);
    float2 gg = *reinterpret_cast<const float2*>(&g[t*2]);
    float2 bb = *reinterpret_cast<const float2*>(&bta[t*2]);
    short2 o; o.x = f2bf((v.x-mu)*rs*gg.x + bb.x); o.y = f2bf((v.y-mu)*rs*gg.y + bb.y);
    *reinterpret_cast<short2*>(&y[(size_t)row*512 + t*2]) = o;
}

// ---------------- fp32 W[K][N] -> bf16 W^T[N][K] ----------------
__global__ __launch_bounds__(256) void wconv_t(const float* __restrict__ W,
    short* __restrict__ WT, int K, int N)
{
    __shared__ float t[32][33];
    int bn = blockIdx.x * 32, bk = blockIdx.y * 32;
    int c = threadIdx.x & 31, r8 = threadIdx.x >> 5;
    #pragma unroll
    for (int i = 0; i < 4; ++i) {
        int r = r8 + i*8;
        t[r][c] = W[(size_t)(bk + r)*N + bn + c];
    }
    __syncthreads();
    #pragma unroll
    for (int i = 0; i < 4; ++i) {
        int r = r8 + i*8;
        WT[(size_t)(bn + r)*K + bk + c] = f2bf(t[c][r]);
    }
}

// ---------------- o[i] = a[i] + bias[i % 512]  (f32, vectorized) ----------------
__global__ __launch_bounds__(256) void addbias_f32(const float* __restrict__ a,
    const float* __restrict__ bias, float* __restrict__ o)
{
    int e = (blockIdx.x*256 + threadIdx.x)*4;
    float4 av = *reinterpret_cast<const float4*>(a + e);
    float4 bv = *reinterpret_cast<const float4*>(bias + (e & 511));
    float4 ov = {av.x+bv.x, av.y+bv.y, av.z+bv.z, av.w+bv.w};
    *reinterpret_cast<float4*>(o + e) = ov;
}

// ---------------- pack padding mask into per-(row, 64-tile) bit masks ----------
__global__ __launch_bounds__(256) void mask_pack(const unsigned char* __restrict__ m,
    unsigned long long* __restrict__ mb)
{
    int gw = blockIdx.x*4 + (threadIdx.x >> 6);   // 32768 waves
    int row = gw >> 4, jt = gw & 15, j = threadIdx.x & 63;
    unsigned char v = m[(size_t)row*NTOK + jt*64 + j];
    unsigned long long bits = __ballot(v != 0);
    if (j == 0) mb[(size_t)row*16 + jt] = bits;
}

// ---------------- rnT[b*1024+j][i] = |c[b,i]-c[b,j]| as bf16 (head-independent) --
__global__ __launch_bounds__(256) void rn_pre(const float* __restrict__ coords,
    short* __restrict__ rnT)
{
    int row = blockIdx.x;                    // b*1024 + j
    int b = row >> 10;
    float2 cj = *reinterpret_cast<const float2*>(&coords[(size_t)row*2]);
    int i0 = threadIdx.x * 4;
    float4 a = *reinterpret_cast<const float4*>(&coords[(size_t)(b*1024 + i0)*2]);
    float4 d = *reinterpret_cast<const float4*>(&coords[(size_t)(b*1024 + i0 + 2)*2]);
    short4 o;
    o.x = f2bf(sqrtf((a.x-cj.x)*(a.x-cj.x) + (a.y-cj.y)*(a.y-cj.y)));
    o.y = f2bf(sqrtf((a.z-cj.x)*(a.z-cj.x) + (a.w-cj.y)*(a.w-cj.y)));
    o.z = f2bf(sqrtf((d.x-cj.x)*(d.x-cj.x) + (d.y-cj.y)*(d.y-cj.y)));
    o.w = f2bf(sqrtf((d.z-cj.x)*(d.z-cj.x) + (d.w-cj.y)*(d.w-cj.y)));
    *reinterpret_cast<short4*>(&rnT[(size_t)row*1024 + i0]) = o;
}

// ---------------- bf16 MFMA GEMM, 64x64 tile, BK=64, 3-stage counted-vmcnt ----
// raw s_barrier (NOT __syncthreads) so the counted vmcnt pipeline stays live.
template<int EPI, bool OUTBF, bool BIAS_ROW, int SPLITK, bool QSC, int NT>
__global__ __launch_bounds__(256) void gemm64(
    const short* __restrict__ A, const short* __restrict__ BT,
    const float* __restrict__ bias, void* __restrict__ Cout,
    int M, int N, int K, int nbx)
{
    __shared__ sh8 As8[3][512];
    __shared__ sh8 Bs8[3][512];
    int tid = threadIdx.x;
    int w = tid >> 6, lane = tid & 63, lr = lane & 15, lg = lane >> 4;
    int wr = w >> 1, wc = w & 1;
    int cpx = gridDim.x >> 3;
    int swz = (blockIdx.x & 7)*cpx + (blockIdx.x >> 3);
    int bx = swz % nbx, by = swz / nbx;
    int bm0 = by*64, bn0 = bx*64;
    int kbeg = (K / SPLITK) * blockIdx.z;

    f32x4 zero = {0.f,0.f,0.f,0.f};
    f32x4 acc[2][2];
    #pragma unroll
    for (int m = 0; m < 2; ++m)
        #pragma unroll
        for (int n = 0; n < 2; ++n) acc[m][n] = zero;

    #define STAGE(buf, k0) { \
        _Pragma("unroll") \
        for (int it = 0; it < 2; ++it) { \
            int s = tid + it*256; \
            int r = s >> 3, g = s & 7; \
            int ksw = (k0) + ((g ^ (r & 7)) << 3); \
            aload16(&As8[buf][s], A  + (size_t)(bm0 + r)*K + ksw); \
            aload16(&Bs8[buf][s], BT + (size_t)(bn0 + r)*K + ksw); \
        } }

    STAGE(0, kbeg)
    if (NT > 1) STAGE(1, kbeg + 64)

    #pragma unroll
    for (int t = 0; t < NT; ++t) {
        if (t + 1 < NT) asm volatile("s_waitcnt vmcnt(4)" ::: "memory");
        else            asm volatile("s_waitcnt vmcnt(0)" ::: "memory");
        __builtin_amdgcn_s_barrier();
        __builtin_amdgcn_sched_barrier(0);
        int buf = t % 3;
        sh8 af[2][2], bfv[2][2];
        #pragma unroll
        for (int m = 0; m < 2; ++m) {
            int R = wr*32 + m*16 + lr;
            #pragma unroll
            for (int s = 0; s < 2; ++s) af[m][s] = As8[buf][R*8 + ((s*4+lg) ^ (R & 7))];
        }
        #pragma unroll
        for (int n = 0; n < 2; ++n) {
            int R = wc*32 + n*16 + lr;
            #pragma unroll
            for (int s = 0; s < 2; ++s) bfv[n][s] = Bs8[buf][R*8 + ((s*4+lg) ^ (R & 7))];
        }
        if (t + 2 < NT) STAGE((t+2)%3, kbeg + (t+2)*64)
        #pragma unroll
        for (int m = 0; m < 2; ++m)
            #pragma unroll
            for (int n = 0; n < 2; ++n)
                #pragma unroll
                for (int s = 0; s < 2; ++s)
                    acc[m][n] = mfma16(af[m][s], bfv[n][s], acc[m][n]);
        asm volatile("s_waitcnt lgkmcnt(0)" ::: "memory");
    }
    #undef STAGE

    #pragma unroll
    for (int m = 0; m < 2; ++m) {
        #pragma unroll
        for (int n = 0; n < 2; ++n) {
            #pragma unroll
            for (int r = 0; r < 4; ++r) {
                int row = bm0 + wr*32 + m*16 + lg*4 + r;
                int col = bn0 + wc*32 + n*16 + lr;
                if (EPI == 3) {
                    atomicAdd((float*)Cout + (size_t)row*N + col, acc[m][n][r]);
                } else {
                    float v = acc[m][n][r] + (BIAS_ROW ? bias[row] : bias[col]);
                    if (QSC && col < 512) v *= (0.125f * LOG2E);
                    if (EPI == 2) v = 0.5f * v * (1.0f + erff(v * 0.70710678f));
                    if (OUTBF) ((short*)Cout)[(size_t)row*N + col] = f2bf(v);
                    else       ((float*)Cout)[(size_t)row*N + col] = v;
                }
            }
        }
    }
}

// ---------------- LDS-staged MFMA flash attention, KV-split x2 ----------------
// 4 waves/block share K/V tiles staged via global_load_lds (3-buffer, counted
// vmcnt, raw s_barrier). Each wave owns 16 q rows. No K/V registers -> no spill.
__global__ __launch_bounds__(256) void attn_reg(
    const short* __restrict__ qk, const short* __restrict__ vt,
    const short* __restrict__ rnT, const unsigned long long* __restrict__ mb64,
    const float* __restrict__ w_edge, short* __restrict__ Op, float* __restrict__ ml)
{
    __shared__ sh8 Ks8[3][512];   // [64 k][8 slots 16B] swizzled
    __shared__ sh8 Vs8[3][512];   // [64 d][8 slots 16B] swizzled
    __shared__ sh8 Ps8[4][128];   // per-wave P tile [16 q][64 k], swizzled

    int swz = (blockIdx.x & 7)*64 + (blockIdx.x >> 3);   // 512 blocks, bijective
    int w = threadIdx.x >> 6, lane = threadIdx.x & 63;
    int lr = lane & 15, lg = lane >> 4;
    int qb = swz & 15;          // q block of 64 rows
    int h  = (swz >> 4) & 7;
    int b  = (swz >> 7) & 1;
    int ks = swz >> 8;          // KV split 0/1

    const int q0 = qb*64 + w*16;          // within-batch q base for this wave
    const int qrow0 = b*NTOK + q0;

    sh8 qf[2];
    #pragma unroll
    for (int s = 0; s < 2; ++s)
        qf[s] = *reinterpret_cast<const sh8*>(qk + (size_t)(qrow0 + lr)*1024 + h*64 + s*32 + lg*8);

    float we2l = w_edge[2*NHEADS + h] * LOG2E;

    float m_i[4], l_lane[4];
    f32x4 zero = {0.f,0.f,0.f,0.f};
    f32x4 accO[4];
    #pragma unroll
    for (int r = 0; r < 4; ++r) { m_i[r] = -1e30f; l_lane[r] = 0.f; }
    #pragma unroll
    for (int n = 0; n < 4; ++n) accO[n] = zero;

    const short* kbase = qk + 512 + h*64;
    const short* vbase = vt + (size_t)h*64*2048 + b*NTOK;
    int sr = threadIdx.x >> 3, sg = threadIdx.x & 7;   // staging row/slot for tid
    int sx = (sg ^ (sr & 7)) << 3;                     // swizzled element offset

    #define ASTAGE(bf, jt) { \
        aload16(&Ks8[bf][threadIdx.x],       kbase + (size_t)(b*NTOK + (jt)*64 + sr)*1024 + sx); \
        aload16(&Ks8[bf][threadIdx.x + 256], kbase + (size_t)(b*NTOK + (jt)*64 + sr + 32)*1024 + sx); \
        aload16(&Vs8[bf][threadIdx.x],       vbase + (size_t)sr*2048 + (jt)*64 + sx); \
        aload16(&Vs8[bf][threadIdx.x + 256], vbase + (size_t)(sr + 32)*2048 + (jt)*64 + sx); \
    }

    const int jt0 = ks*8;
    ASTAGE(0, jt0)
    ASTAGE(1, jt0 + 1)

    #pragma unroll
    for (int t = 0; t < 8; ++t) {
        if (t + 1 < 8) asm volatile("s_waitcnt vmcnt(4)" ::: "memory");
        else           asm volatile("s_waitcnt vmcnt(0)" ::: "memory");
        __builtin_amdgcn_s_barrier();
        __builtin_amdgcn_sched_barrier(0);
        int buf = t % 3;
        int jt = jt0 + t;

        if (t + 2 < 8) ASTAGE((t+2)%3, jt0 + t + 2)

        // radial-norm (precomputed bf16, transposed) + mask bits
        short4 rnp[4];
        #pragma unroll
        for (int n = 0; n < 4; ++n)
            rnp[n] = *reinterpret_cast<const short4*>(
                &rnT[(size_t)(b*1024 + jt*64 + n*16 + lr)*1024 + q0 + lg*4]);
        unsigned long long mrow[4];
        #pragma unroll
        for (int r = 0; r < 4; ++r)
            mrow[r] = mb64[(size_t)(qrow0 + lg*4 + r)*16 + jt];

        // S = Q K^T (q pre-scaled by 0.125*log2e); K frags from LDS
        f32x4 Sv[4];
        #pragma unroll
        for (int n = 0; n < 4; ++n) {
            int kcol = n*16 + lr;
            sh8 k0v = Ks8[buf][kcol*8 + (lg       ^ (kcol & 7))];
            sh8 k1v = Ks8[buf][kcol*8 + ((4 + lg) ^ (kcol & 7))];
            Sv[n] = mfma16(qf[1], k1v, mfma16(qf[0], k0v, zero));
        }

        // radial bias + mask (log2 domain)
        #pragma unroll
        for (int n = 0; n < 4; ++n) {
            #pragma unroll
            for (int r = 0; r < 4; ++r) {
                short rnb = (r == 0) ? rnp[n].x : (r == 1) ? rnp[n].y
                          : (r == 2) ? rnp[n].z : rnp[n].w;
                float sv = fmaf(bf2f(rnb), we2l, Sv[n][r]);
                Sv[n][r] = ((mrow[r] >> (n*16 + lr)) & 1ull) ? -1e9f : sv;
            }
        }

        // online softmax (row = 16 lanes sharing lg); lane-local l
        #pragma unroll
        for (int r = 0; r < 4; ++r) {
            float mx = fmaxf(fmaxf(Sv[0][r], Sv[1][r]), fmaxf(Sv[2][r], Sv[3][r]));
            #pragma unroll
            for (int msk = 1; msk < 16; msk <<= 1) mx = fmaxf(mx, __shfl_xor(mx, msk));
            float mnew = fmaxf(m_i[r], mx);
            float f = ex2(m_i[r] - mnew);
            m_i[r] = mnew;
            float rs = 0.f;
            #pragma unroll
            for (int n = 0; n < 4; ++n) { float p = ex2(Sv[n][r] - mnew); Sv[n][r] = p; rs += p; }
            l_lane[r] = l_lane[r]*f + rs;
            #pragma unroll
            for (int n = 0; n < 4; ++n) accO[n][r] *= f;
        }

        // P -> wave-private LDS (swizzled), reload as A fragments
        short* Pw = (short*)&Ps8[w][0];
        #pragma unroll
        for (int r = 0; r < 4; ++r) {
            int q = lg*4 + r;
            #pragma unroll
            for (int n = 0; n < 4; ++n) {
                int k = n*16 + lr;
                Pw[q*64 + (((k>>3) ^ (q&7)) << 3) + (k&7)] = f2bf(Sv[n][r]);
            }
        }
        sh8 pa[2];
        #pragma unroll
        for (int s = 0; s < 2; ++s)
            pa[s] = Ps8[w][lr*8 + ((s*4 + lg) ^ (lr & 7))];

        // PV; V frags from LDS
        #pragma unroll
        for (int n = 0; n < 4; ++n) {
            int dcol = n*16 + lr;
            sh8 v0 = Vs8[buf][dcol*8 + (lg       ^ (dcol & 7))];
            sh8 v1 = Vs8[buf][dcol*8 + ((4 + lg) ^ (dcol & 7))];
            accO[n] = mfma16(pa[1], v1, mfma16(pa[0], v0, accO[n]));
        }

        asm volatile("s_waitcnt lgkmcnt(0)" ::: "memory");
    }
    #undef ASTAGE

    // reduce l once
    #pragma unroll
    for (int r = 0; r < 4; ++r) {
        float ls = l_lane[r];
        #pragma unroll
        for (int msk = 1; msk < 16; msk <<= 1) ls += __shfl_xor(ls, msk);
        l_lane[r] = ls;
    }

    // partials: unnormalized bf16 O + (m, l)
    #pragma unroll
    for (int r = 0; r < 4; ++r) {
        size_t row = (size_t)(ks*MTOK + qrow0 + lg*4 + r);
        #pragma unroll
        for (int n = 0; n < 4; ++n)
            Op[row*512 + h*64 + n*16 + lr] = f2bf(accO[n][r]);
        if (lr == 0) {
            ml[(row*NHEADS + h)*2 + 0] = m_i[r];
            ml[(row*NHEADS + h)*2 + 1] = l_lane[r];
        }
    }
}

// ---------------- combine 2 KV-split partials -> bf16 O (log2-domain m) -------
__global__ __launch_bounds__(256) void attn_combine(const short* __restrict__ Op,
    const float* __restrict__ ml, short* __restrict__ ob)
{
    int idx = blockIdx.x*256 + threadIdx.x;     // MTOK*128 threads
    int tok = idx >> 7, dd = (idx & 127) * 4;
    int h = dd >> 6;
    float m0 = ml[((size_t)tok*NHEADS + h)*2 + 0];
    float l0 = ml[((size_t)tok*NHEADS + h)*2 + 1];
    float m1 = ml[(((size_t)MTOK + tok)*NHEADS + h)*2 + 0];
    float l1 = ml[(((size_t)MTOK + tok)*NHEADS + h)*2 + 1];
    float mm = fmaxf(m0, m1);
    float w0 = ex2(m0 - mm), w1 = ex2(m1 - mm);
    float inv = 1.f / (w0*l0 + w1*l1);
    short4 a = *reinterpret_cast<const short4*>(&Op[(size_t)tok*512 + dd]);
    short4 c = *reinterpret_cast<const short4*>(&Op[((size_t)MTOK + tok)*512 + dd]);
    short4 o;
    o.x = f2bf((bf2f(a.x)*w0 + bf2f(c.x)*w1)*inv);
    o.y = f2bf((bf2f(a.y)*w0 + bf2f(c.y)*w1)*inv);
    o.z = f2bf((bf2f(a.z)*w0 + bf2f(c.z)*w1)*inv);
    o.w = f2bf((bf2f(a.w)*w0 + bf2f(c.w)*w1)*inv);
    *reinterpret_cast<short4*>(&ob[(size_t)tok*512 + dd]) = o;
}

// -------------------------------------------------------------------------------
extern "C" void kernel_launch(void* const* d_in, const int* in_sizes, int n_in,
                              void* d_out, int out_size, void* d_ws, size_t ws_size,
                              hipStream_t stream)
{
    const float* x      = (const float*)d_in[0];
    const float* coords = (const float*)d_in[1];
    const unsigned char* mask = (const unsigned char*)d_in[2];
    const float* ln1_g = (const float*)d_in[3];
    const float* ln1_b = (const float*)d_in[4];
    const float* w_qkv = (const float*)d_in[5];
    const float* b_qkv = (const float*)d_in[6];
    const float* w_edge= (const float*)d_in[7];
    const float* w_out = (const float*)d_in[8];
    const float* b_out = (const float*)d_in[9];
    const float* ln2_g = (const float*)d_in[10];
    const float* ln2_b = (const float*)d_in[11];
    const float* w1    = (const float*)d_in[12];
    const float* b1    = (const float*)d_in[13];
    const float* w2    = (const float*)d_in[14];
    const float* b2    = (const float*)d_in[15];
    float* out = (float*)d_out;

    char* W = (char*)d_ws;
    const size_t MB = 1024*1024;
    float* x1    = (float*)(W);                    // [0,4M) f32
    short* qk    = (short*)(W + 4*MB);             // [4M,8M)
    short* vtb   = (short*)(W + 8*MB);             // [8M,10M)
    short* woutT = (short*)(W + 10*MB);            // [10M,10.5M)
    short* xln   = (short*)(W + 10*MB + 512*1024); // [10.5M,12.5M)  (later y)
    short* wqkvT = (short*)(W + 12*MB + 512*1024); // [12.5M,14M)
    short* Opart = (short*)(W + 14*MB + 512*1024); // [14.5M,18.5M) bf16 2x2048x512
    short* rnT   = (short*)(W + 18*MB + 512*1024); // [18.5M,22.5M) bf16 2048x1024
    float* mlp   = (float*)(W + 22*MB + 512*1024); // [22.5M,22.75M)
    unsigned long long* mb64 = (unsigned long long*)(W + 23*MB); // [23M,23.25M)
    short* ob    = (short*)(W + 6*MB);             // [6M,8M)  (qk dead after attn)
    short* y     = xln;
    short* w1T   = (short*)(W + 4*MB);             // [4M,6M)  (qk dead)
    short* w2T   = (short*)(W + 8*MB);             // [8M,10M) (vtb dead)
    short* hid   = (short*)(W + 14*MB + 512*1024); // [14.5M,22.5M) (Opart/rnT dead)

    // ---- phase 1 ----
    mask_pack<<<dim3(8192,1,1), 256, 0, stream>>>(mask, mb64);
    rn_pre<<<dim3(2048,1,1), 256, 0, stream>>>(coords, rnT);
    wconv_t<<<dim3(1536/32, 512/32), 256, 0, stream>>>(w_qkv, wqkvT, 512, 1536);
    wconv_t<<<dim3(512/32, 512/32), 256, 0, stream>>>(w_out, woutT, 512, 512);
    ln_bf16<<<MTOK, 256, 0, stream>>>(x, ln1_g, ln1_b, xln);
    gemm64<0,true,false,1,true,8><<<dim3(512,1,1), 256, 0, stream>>>(
        xln, wqkvT, b_qkv, qk, MTOK, 1024, 512, 16);
    gemm64<0,true,true,1,false,8><<<dim3(256,1,1), 256, 0, stream>>>(
        wqkvT + (size_t)1024*512, xln, b_qkv + 1024, vtb, 512, MTOK, 512, 32);
    attn_reg<<<dim3(512,1,1), 256, 0, stream>>>(qk, vtb, rnT, mb64, w_edge, Opart, mlp);
    attn_combine<<<dim3(1024,1,1), 256, 0, stream>>>(Opart, mlp, ob);
    addbias_f32<<<1024, 256, 0, stream>>>(x, b_out, x1);
    gemm64<3,false,false,2,false,4><<<dim3(256,1,2), 256, 0, stream>>>(
        ob, woutT, nullptr, x1, MTOK, 512, 512, 8);
    // ---- phase 2 ----
    wconv_t<<<dim3(2048/32, 512/32), 256, 0, stream>>>(w1, w1T, 512, 2048);
    wconv_t<<<dim3(512/32, 2048/32), 256, 0, stream>>>(w2, w2T, 2048, 512);
    ln_bf16<<<MTOK, 256, 0, stream>>>(x1, ln2_g, ln2_b, y);
    gemm64<2,true,false,1,false,8><<<dim3(1024,1,1), 256, 0, stream>>>(
        y, w1T, b1, hid, MTOK, 2048, 512, 32);
    addbias_f32<<<1024, 256, 0, stream>>>(x1, b2, out);
    gemm64<3,false,false,4,false,8><<<dim3(256,1,4), 256, 0, stream>>>(
        hid, w2T, nullptr, out, MTOK, 512, 2048, 8);
}

// Round 10
// 112.702 us; speedup vs baseline: 1.2201x; 1.0152x over previous
//
#include <hip/hip_runtime.h>
#include <hip/hip_bf16.h>
#include <math.h>

#define NHEADS 8
#define NTOK   1024
#define MTOK   2048

typedef __attribute__((ext_vector_type(8))) short  sh8;
typedef __attribute__((ext_vector_type(8))) __bf16 bf16x8;
typedef __attribute__((ext_vector_type(4))) float  f32x4;

__device__ __forceinline__ short f2bf(float v) {
    return __builtin_bit_cast(short, __float2bfloat16(v));
}
__device__ __forceinline__ float bf2f(short v) {
    return __builtin_bit_cast(float, ((unsigned)(unsigned short)v) << 16);
}
__device__ __forceinline__ float ex2(float v) {
    return __builtin_amdgcn_exp2f(v);
}
__device__ __forceinline__ f32x4 mfma16(sh8 a, sh8 b, f32x4 c) {
    return __builtin_amdgcn_mfma_f32_16x16x32_bf16(
        __builtin_bit_cast(bf16x8, a), __builtin_bit_cast(bf16x8, b), c, 0, 0, 0);
}
__device__ __forceinline__ void aload16(void* lds, const void* g) {
    __builtin_amdgcn_global_load_lds(
        (const __attribute__((address_space(1))) unsigned int*)g,
        (__attribute__((address_space(3))) unsigned int*)lds, 16, 0, 0);
}

#define LOG2E 1.4426950408889634f

// ---------------- LayerNorm -> bf16 (optionally fuse resout = x + bias2) -------
template<bool FUSE>
__global__ __launch_bounds__(256) void ln_bf16(const float* __restrict__ x,
    const float* __restrict__ g, const float* __restrict__ bta, short* __restrict__ y,
    const float* __restrict__ bias2, float* __restrict__ resout)
{
    int row = blockIdx.x, t = threadIdx.x;
    const float* xr = x + (size_t)row * 512;
    float2 v = *reinterpret_cast<const float2*>(&xr[t*2]);
    float s = v.x + v.y, ss = v.x*v.x + v.y*v.y;
    #pragma unroll
    for (int m = 1; m < 64; m <<= 1) { s += __shfl_xor(s, m); ss += __shfl_xor(ss, m); }
    __shared__ float red[8];
    int wid = t >> 6, lane = t & 63;
    if (!lane) { red[wid] = s; red[4+wid] = ss; }
    __syncthreads();
    s = red[0]+red[1]+red[2]+red[3]; ss = red[4]+red[5]+red[6]+red[7];
    float mu = s*(1.f/512), var = ss*(1.f/512) - mu*mu, rs = rsqrtf(var + 1e-5f);
    float2 gg = *reinterpret_cast<const float2*>(&g[t*2]);
    float2 bb = *reinterpret_cast<const float2*>(&bta[t*2]);
    short2 o; o.x = f2bf((v.x-mu)*rs*gg.x + bb.x); o.y = f2bf((v.y-mu)*rs*gg.y + bb.y);
    *reinterpret_cast<short2*>(&y[(size_t)row*512 + t*2]) = o;
    if (FUSE) {
        float2 b2 = *reinterpret_cast<const float2*>(&bias2[t*2]);
        float2 ro = {v.x + b2.x, v.y + b2.y};
        *reinterpret_cast<float2*>(&resout[(size_t)row*512 + t*2]) = ro;
    }
}

// ---------------- fp32 W[K][N] -> bf16 W^T[N][K] ----------------
__global__ __launch_bounds__(256) void wconv_t(const float* __restrict__ W,
    short* __restrict__ WT, int K, int N)
{
    __shared__ float t[32][33];
    int bn = blockIdx.x * 32, bk = blockIdx.y * 32;
    int c = threadIdx.x & 31, r8 = threadIdx.x >> 5;
    #pragma unroll
    for (int i = 0; i < 4; ++i) {
        int r = r8 + i*8;
        t[r][c] = W[(size_t)(bk + r)*N + bn + c];
    }
    __syncthreads();
    #pragma unroll
    for (int i = 0; i < 4; ++i) {
        int r = r8 + i*8;
        WT[(size_t)(bn + r)*K + bk + c] = f2bf(t[c][r]);
    }
}

// ---------------- pack padding mask into per-(row, 64-tile) bit masks ----------
__global__ __launch_bounds__(256) void mask_pack(const unsigned char* __restrict__ m,
    unsigned long long* __restrict__ mb)
{
    int gw = blockIdx.x*4 + (threadIdx.x >> 6);   // 32768 waves
    int row = gw >> 4, jt = gw & 15, j = threadIdx.x & 63;
    unsigned char v = m[(size_t)row*NTOK + jt*64 + j];
    unsigned long long bits = __ballot(v != 0);
    if (j == 0) mb[(size_t)row*16 + jt] = bits;
}

// ---------------- rnT[b*1024+j][i] = |c[b,i]-c[b,j]| as bf16 (head-independent) --
__global__ __launch_bounds__(256) void rn_pre(const float* __restrict__ coords,
    short* __restrict__ rnT)
{
    int row = blockIdx.x;                    // b*1024 + j
    int b = row >> 10;
    float2 cj = *reinterpret_cast<const float2*>(&coords[(size_t)row*2]);
    int i0 = threadIdx.x * 4;
    float4 a = *reinterpret_cast<const float4*>(&coords[(size_t)(b*1024 + i0)*2]);
    float4 d = *reinterpret_cast<const float4*>(&coords[(size_t)(b*1024 + i0 + 2)*2]);
    short4 o;
    o.x = f2bf(sqrtf((a.x-cj.x)*(a.x-cj.x) + (a.y-cj.y)*(a.y-cj.y)));
    o.y = f2bf(sqrtf((a.z-cj.x)*(a.z-cj.x) + (a.w-cj.y)*(a.w-cj.y)));
    o.z = f2bf(sqrtf((d.x-cj.x)*(d.x-cj.x) + (d.y-cj.y)*(d.y-cj.y)));
    o.w = f2bf(sqrtf((d.z-cj.x)*(d.z-cj.x) + (d.w-cj.y)*(d.w-cj.y)));
    *reinterpret_cast<short4*>(&rnT[(size_t)row*1024 + i0]) = o;
}

// ---------------- bf16 MFMA GEMM, 64x64 tile, BK=64, 3-stage counted-vmcnt ----
template<int EPI, bool OUTBF, bool BIAS_ROW, int SPLITK, bool QSC, int NT>
__global__ __launch_bounds__(256) void gemm64(
    const short* __restrict__ A, const short* __restrict__ BT,
    const float* __restrict__ bias, void* __restrict__ Cout,
    int M, int N, int K, int nbx)
{
    __shared__ sh8 As8[3][512];
    __shared__ sh8 Bs8[3][512];
    int tid = threadIdx.x;
    int w = tid >> 6, lane = tid & 63, lr = lane & 15, lg = lane >> 4;
    int wr = w >> 1, wc = w & 1;
    int cpx = gridDim.x >> 3;
    int swz = (blockIdx.x & 7)*cpx + (blockIdx.x >> 3);
    int bx = swz % nbx, by = swz / nbx;
    int bm0 = by*64, bn0 = bx*64;
    int kbeg = (K / SPLITK) * blockIdx.z;

    f32x4 zero = {0.f,0.f,0.f,0.f};
    f32x4 acc[2][2];
    #pragma unroll
    for (int m = 0; m < 2; ++m)
        #pragma unroll
        for (int n = 0; n < 2; ++n) acc[m][n] = zero;

    #define STAGE(buf, k0) { \
        _Pragma("unroll") \
        for (int it = 0; it < 2; ++it) { \
            int s = tid + it*256; \
            int r = s >> 3, g = s & 7; \
            int ksw = (k0) + ((g ^ (r & 7)) << 3); \
            aload16(&As8[buf][s], A  + (size_t)(bm0 + r)*K + ksw); \
            aload16(&Bs8[buf][s], BT + (size_t)(bn0 + r)*K + ksw); \
        } }

    STAGE(0, kbeg)
    if (NT > 1) STAGE(1, kbeg + 64)

    #pragma unroll
    for (int t = 0; t < NT; ++t) {
        if (t + 1 < NT) asm volatile("s_waitcnt vmcnt(4)" ::: "memory");
        else            asm volatile("s_waitcnt vmcnt(0)" ::: "memory");
        __builtin_amdgcn_s_barrier();
        __builtin_amdgcn_sched_barrier(0);
        int buf = t % 3;
        sh8 af[2][2], bfv[2][2];
        #pragma unroll
        for (int m = 0; m < 2; ++m) {
            int R = wr*32 + m*16 + lr;
            #pragma unroll
            for (int s = 0; s < 2; ++s) af[m][s] = As8[buf][R*8 + ((s*4+lg) ^ (R & 7))];
        }
        #pragma unroll
        for (int n = 0; n < 2; ++n) {
            int R = wc*32 + n*16 + lr;
            #pragma unroll
            for (int s = 0; s < 2; ++s) bfv[n][s] = Bs8[buf][R*8 + ((s*4+lg) ^ (R & 7))];
        }
        if (t + 2 < NT) STAGE((t+2)%3, kbeg + (t+2)*64)
        #pragma unroll
        for (int m = 0; m < 2; ++m)
            #pragma unroll
            for (int n = 0; n < 2; ++n)
                #pragma unroll
                for (int s = 0; s < 2; ++s)
                    acc[m][n] = mfma16(af[m][s], bfv[n][s], acc[m][n]);
        asm volatile("s_waitcnt lgkmcnt(0)" ::: "memory");
    }
    #undef STAGE

    #pragma unroll
    for (int m = 0; m < 2; ++m) {
        #pragma unroll
        for (int n = 0; n < 2; ++n) {
            #pragma unroll
            for (int r = 0; r < 4; ++r) {
                int row = bm0 + wr*32 + m*16 + lg*4 + r;
                int col = bn0 + wc*32 + n*16 + lr;
                if (EPI == 3) {
                    atomicAdd((float*)Cout + (size_t)row*N + col, acc[m][n][r]);
                } else {
                    float v = acc[m][n][r] + (BIAS_ROW ? bias[row] : bias[col]);
                    if (QSC && col < 512) v *= (0.125f * LOG2E);
                    if (EPI == 2) v = 0.5f * v * (1.0f + erff(v * 0.70710678f));
                    if (OUTBF) ((short*)Cout)[(size_t)row*N + col] = f2bf(v);
                    else       ((float*)Cout)[(size_t)row*N + col] = v;
                }
            }
        }
    }
}

// ---------------- LDS-staged MFMA flash attention, KV-split x4 ----------------
// 2-buffer K/V (40KB LDS -> 4 blocks/CU, 16 waves/CU). rnT/mask register-
// prefetched one iteration ahead (issued AFTER stage ops so no vmcnt drain
// crosses the staging loads).
__global__ __launch_bounds__(256) void attn_reg(
    const short* __restrict__ qk, const short* __restrict__ vt,
    const short* __restrict__ rnT, const unsigned long long* __restrict__ mb64,
    const float* __restrict__ w_edge, short* __restrict__ OpA,
    short* __restrict__ OpB, float* __restrict__ ml)
{
    __shared__ sh8 Ks8[2][512];   // [64 k][8 slots 16B] swizzled
    __shared__ sh8 Vs8[2][512];   // [64 d][8 slots 16B] swizzled
    __shared__ sh8 Ps8[4][128];   // per-wave P tile [16 q][64 k], swizzled

    int cpx = gridDim.x >> 3;     // 1024 blocks -> 128
    int swz = (blockIdx.x & 7)*cpx + (blockIdx.x >> 3);
    int w = threadIdx.x >> 6, lane = threadIdx.x & 63;
    int lr = lane & 15, lg = lane >> 4;
    int qb = swz & 15;            // q block of 64 rows
    int h  = (swz >> 4) & 7;
    int b  = (swz >> 7) & 1;
    int ks = swz >> 8;            // KV split 0..3

    const int q0 = qb*64 + w*16;
    const int qrow0 = b*NTOK + q0;
    const int jt0 = ks*4;

    sh8 qf[2];
    #pragma unroll
    for (int s = 0; s < 2; ++s)
        qf[s] = *reinterpret_cast<const sh8*>(qk + (size_t)(qrow0 + lr)*1024 + h*64 + s*32 + lg*8);

    float we2l = w_edge[2*NHEADS + h] * LOG2E;

    float m_i[4], l_lane[4];
    f32x4 zero = {0.f,0.f,0.f,0.f};
    f32x4 accO[4];
    #pragma unroll
    for (int r = 0; r < 4; ++r) { m_i[r] = -1e30f; l_lane[r] = 0.f; }
    #pragma unroll
    for (int n = 0; n < 4; ++n) accO[n] = zero;

    const short* kbase = qk + 512 + h*64;
    const short* vbase = vt + (size_t)h*64*2048 + b*NTOK;
    int sr = threadIdx.x >> 3, sg = threadIdx.x & 7;
    int sx = (sg ^ (sr & 7)) << 3;

    #define ASTAGE(bf, jt) { \
        aload16(&Ks8[bf][threadIdx.x],       kbase + (size_t)(b*NTOK + (jt)*64 + sr)*1024 + sx); \
        aload16(&Ks8[bf][threadIdx.x + 256], kbase + (size_t)(b*NTOK + (jt)*64 + sr + 32)*1024 + sx); \
        aload16(&Vs8[bf][threadIdx.x],       vbase + (size_t)sr*2048 + (jt)*64 + sx); \
        aload16(&Vs8[bf][threadIdx.x + 256], vbase + (size_t)(sr + 32)*2048 + (jt)*64 + sx); \
    }

    // rnT / mask register prefetch buffers (ping-pong, static indices)
    short4 rn_reg[2][4];
    unsigned long long mr_reg[2][4];
    #define RMLOAD(bf, jt) { \
        _Pragma("unroll") \
        for (int n = 0; n < 4; ++n) \
            rn_reg[bf][n] = *reinterpret_cast<const short4*>( \
                &rnT[(size_t)(b*1024 + (jt)*64 + n*16 + lr)*1024 + q0 + lg*4]); \
        _Pragma("unroll") \
        for (int r = 0; r < 4; ++r) \
            mr_reg[bf][r] = mb64[(size_t)(qrow0 + lg*4 + r)*16 + (jt)]; \
    }

    // prologue: tile 0 stage + rm
    ASTAGE(0, jt0)
    RMLOAD(0, jt0)

    #pragma unroll
    for (int t = 0; t < 4; ++t) {
        if (t == 0) asm volatile("s_waitcnt vmcnt(0)" ::: "memory");
        else        asm volatile("s_waitcnt vmcnt(8)" ::: "memory");
        __builtin_amdgcn_s_barrier();
        __builtin_amdgcn_sched_barrier(0);
        int buf = t & 1;

        // issue next tile's staging FIRST, then rm prefetch (so no wait
        // in the next iteration drains past the staging loads)
        if (t + 1 < 4) {
            ASTAGE(buf ^ 1, jt0 + t + 1)
            RMLOAD(buf ^ 1, jt0 + t + 1)
        }

        // S = Q K^T (q pre-scaled by 0.125*log2e); K frags from LDS
        f32x4 Sv[4];
        #pragma unroll
        for (int n = 0; n < 4; ++n) {
            int kcol = n*16 + lr;
            sh8 k0v = Ks8[buf][kcol*8 + (lg       ^ (kcol & 7))];
            sh8 k1v = Ks8[buf][kcol*8 + ((4 + lg) ^ (kcol & 7))];
            Sv[n] = mfma16(qf[1], k1v, mfma16(qf[0], k0v, zero));
        }

        // radial bias + mask (log2 domain), operands prefetched last iter
        #pragma unroll
        for (int n = 0; n < 4; ++n) {
            #pragma unroll
            for (int r = 0; r < 4; ++r) {
                short rnb = (r == 0) ? rn_reg[buf][n].x : (r == 1) ? rn_reg[buf][n].y
                          : (r == 2) ? rn_reg[buf][n].z : rn_reg[buf][n].w;
                float sv = fmaf(bf2f(rnb), we2l, Sv[n][r]);
                Sv[n][r] = ((mr_reg[buf][r] >> (n*16 + lr)) & 1ull) ? -1e9f : sv;
            }
        }

        // online softmax (row = 16 lanes sharing lg); lane-local l
        #pragma unroll
        for (int r = 0; r < 4; ++r) {
            float mx = fmaxf(fmaxf(Sv[0][r], Sv[1][r]), fmaxf(Sv[2][r], Sv[3][r]));
            #pragma unroll
            for (int msk = 1; msk < 16; msk <<= 1) mx = fmaxf(mx, __shfl_xor(mx, msk));
            float mnew = fmaxf(m_i[r], mx);
            float f = ex2(m_i[r] - mnew);
            m_i[r] = mnew;
            float rs = 0.f;
            #pragma unroll
            for (int n = 0; n < 4; ++n) { float p = ex2(Sv[n][r] - mnew); Sv[n][r] = p; rs += p; }
            l_lane[r] = l_lane[r]*f + rs;
            #pragma unroll
            for (int n = 0; n < 4; ++n) accO[n][r] *= f;
        }

        // P -> wave-private LDS (swizzled), reload as A fragments
        short* Pw = (short*)&Ps8[w][0];
        #pragma unroll
        for (int r = 0; r < 4; ++r) {
            int q = lg*4 + r;
            #pragma unroll
            for (int n = 0; n < 4; ++n) {
                int k = n*16 + lr;
                Pw[q*64 + (((k>>3) ^ (q&7)) << 3) + (k&7)] = f2bf(Sv[n][r]);
            }
        }
        sh8 pa[2];
        #pragma unroll
        for (int s = 0; s < 2; ++s)
            pa[s] = Ps8[w][lr*8 + ((s*4 + lg) ^ (lr & 7))];

        // PV; V frags from LDS
        #pragma unroll
        for (int n = 0; n < 4; ++n) {
            int dcol = n*16 + lr;
            sh8 v0 = Vs8[buf][dcol*8 + (lg       ^ (dcol & 7))];
            sh8 v1 = Vs8[buf][dcol*8 + ((4 + lg) ^ (dcol & 7))];
            accO[n] = mfma16(pa[1], v1, mfma16(pa[0], v0, accO[n]));
        }

        asm volatile("s_waitcnt lgkmcnt(0)" ::: "memory");
    }
    #undef ASTAGE
    #undef RMLOAD

    // reduce l once
    #pragma unroll
    for (int r = 0; r < 4; ++r) {
        float ls = l_lane[r];
        #pragma unroll
        for (int msk = 1; msk < 16; msk <<= 1) ls += __shfl_xor(ls, msk);
        l_lane[r] = ls;
    }

    // partials: unnormalized bf16 O + (m, l); splits {0,1}->OpA, {2,3}->OpB
    short* Op = (ks < 2) ? OpA : OpB;
    #pragma unroll
    for (int r = 0; r < 4; ++r) {
        size_t row = (size_t)((ks & 1)*MTOK + qrow0 + lg*4 + r);
        #pragma unroll
        for (int n = 0; n < 4; ++n)
            Op[row*512 + h*64 + n*16 + lr] = f2bf(accO[n][r]);
        if (lr == 0) {
            size_t mrow = (size_t)(ks*MTOK + qrow0 + lg*4 + r);
            ml[(mrow*NHEADS + h)*2 + 0] = m_i[r];
            ml[(mrow*NHEADS + h)*2 + 1] = l_lane[r];
        }
    }
}

// ---------------- combine 4 KV-split partials -> bf16 O; fuse x1 = x + b_out --
__global__ __launch_bounds__(256) void attn_combine4(const short* __restrict__ OpA,
    const short* __restrict__ OpB, const float* __restrict__ ml,
    short* __restrict__ ob, const float* __restrict__ x,
    const float* __restrict__ b_out, float* __restrict__ x1)
{
    int idx = blockIdx.x*256 + threadIdx.x;     // MTOK*128 threads
    int tok = idx >> 7, dd = (idx & 127) * 4;
    int h = dd >> 6;
    float m[4], l[4];
    #pragma unroll
    for (int s = 0; s < 4; ++s) {
        m[s] = ml[(((size_t)s*MTOK + tok)*NHEADS + h)*2 + 0];
        l[s] = ml[(((size_t)s*MTOK + tok)*NHEADS + h)*2 + 1];
    }
    float mm = fmaxf(fmaxf(m[0], m[1]), fmaxf(m[2], m[3]));
    float wsum = 0.f, a0 = 0.f, a1 = 0.f, a2 = 0.f, a3 = 0.f;
    #pragma unroll
    for (int s = 0; s < 4; ++s) {
        float wv = ex2(m[s] - mm);
        wsum += wv * l[s];
        const short* Op = (s < 2) ? OpA : OpB;
        short4 p = *reinterpret_cast<const short4*>(&Op[((size_t)((s&1)*MTOK) + tok)*512 + dd]);
        a0 += bf2f(p.x)*wv; a1 += bf2f(p.y)*wv;
        a2 += bf2f(p.z)*wv; a3 += bf2f(p.w)*wv;
    }
    float inv = 1.f / wsum;
    short4 o;
    o.x = f2bf(a0*inv); o.y = f2bf(a1*inv);
    o.z = f2bf(a2*inv); o.w = f2bf(a3*inv);
    *reinterpret_cast<short4*>(&ob[(size_t)tok*512 + dd]) = o;
    // fused residual-bias init: x1 = x + b_out
    float4 xv = *reinterpret_cast<const float4*>(&x[(size_t)tok*512 + dd]);
    float4 bv = *reinterpret_cast<const float4*>(&b_out[dd]);
    float4 xo = {xv.x+bv.x, xv.y+bv.y, xv.z+bv.z, xv.w+bv.w};
    *reinterpret_cast<float4*>(&x1[(size_t)tok*512 + dd]) = xo;
}

// -------------------------------------------------------------------------------
extern "C" void kernel_launch(void* const* d_in, const int* in_sizes, int n_in,
                              void* d_out, int out_size, void* d_ws, size_t ws_size,
                              hipStream_t stream)
{
    const float* x      = (const float*)d_in[0];
    const float* coords = (const float*)d_in[1];
    const unsigned char* mask = (const unsigned char*)d_in[2];
    const float* ln1_g = (const float*)d_in[3];
    const float* ln1_b = (const float*)d_in[4];
    const float* w_qkv = (const float*)d_in[5];
    const float* b_qkv = (const float*)d_in[6];
    const float* w_edge= (const float*)d_in[7];
    const float* w_out = (const float*)d_in[8];
    const float* b_out = (const float*)d_in[9];
    const float* ln2_g = (const float*)d_in[10];
    const float* ln2_b = (const float*)d_in[11];
    const float* w1    = (const float*)d_in[12];
    const float* b1    = (const float*)d_in[13];
    const float* w2    = (const float*)d_in[14];
    const float* b2    = (const float*)d_in[15];
    float* out = (float*)d_out;

    char* W = (char*)d_ws;
    const size_t MB = 1024*1024;
    float* x1    = (float*)(W);                    // [0,4M) f32 (written post-attn)
    short* qk    = (short*)(W + 4*MB);             // [4M,8M)
    short* vtb   = (short*)(W + 8*MB);             // [8M,10M)
    short* woutT = (short*)(W + 10*MB);            // [10M,10.5M)
    short* xln   = (short*)(W + 10*MB + 512*1024); // [10.5M,12.5M)  (later y)
    short* wqkvT = (short*)(W + 12*MB + 512*1024); // [12.5M,14M)
    short* OpB   = (short*)(W + 10*MB + 512*1024); // [10.5M,14.5M) over dead xln/wqkvT
    short* OpA   = (short*)(W + 14*MB + 512*1024); // [14.5M,18.5M)
    short* rnT   = (short*)(W + 18*MB + 512*1024); // [18.5M,22.5M) bf16 2048x1024
    float* mlp   = (float*)(W + 22*MB + 512*1024); // [22.5M,23M) 4x2048x8x2 f32
    unsigned long long* mb64 = (unsigned long long*)(W + 23*MB); // [23M,23.25M)
    short* ob    = (short*)(W + 6*MB);             // [6M,8M)  (qk dead after attn)
    short* y     = xln;                            // [10.5M,12.5M) (OpB dead)
    short* w1T   = (short*)(W + 4*MB);             // [4M,6M)  (qk dead)
    short* w2T   = (short*)(W + 8*MB);             // [8M,10M) (vtb dead)
    short* hid   = (short*)(W + 14*MB + 512*1024); // [14.5M,22.5M) (OpA/rnT dead)

    // ---- phase 1 ----
    mask_pack<<<dim3(8192,1,1), 256, 0, stream>>>(mask, mb64);
    rn_pre<<<dim3(2048,1,1), 256, 0, stream>>>(coords, rnT);
    wconv_t<<<dim3(1536/32, 512/32), 256, 0, stream>>>(w_qkv, wqkvT, 512, 1536);
    wconv_t<<<dim3(512/32, 512/32), 256, 0, stream>>>(w_out, woutT, 512, 512);
    ln_bf16<false><<<MTOK, 256, 0, stream>>>(x, ln1_g, ln1_b, xln, nullptr, nullptr);
    gemm64<0,true,false,1,true,8><<<dim3(512,1,1), 256, 0, stream>>>(
        xln, wqkvT, b_qkv, qk, MTOK, 1024, 512, 16);
    gemm64<0,true,true,1,false,8><<<dim3(256,1,1), 256, 0, stream>>>(
        wqkvT + (size_t)1024*512, xln, b_qkv + 1024, vtb, 512, MTOK, 512, 32);
    attn_reg<<<dim3(1024,1,1), 256, 0, stream>>>(qk, vtb, rnT, mb64, w_edge, OpA, OpB, mlp);
    attn_combine4<<<dim3(1024,1,1), 256, 0, stream>>>(OpA, OpB, mlp, ob, x, b_out, x1);
    gemm64<3,false,false,2,false,4><<<dim3(256,1,2), 256, 0, stream>>>(
        ob, woutT, nullptr, x1, MTOK, 512, 512, 8);
    // ---- phase 2 ----
    wconv_t<<<dim3(2048/32, 512/32), 256, 0, stream>>>(w1, w1T, 512, 2048);
    wconv_t<<<dim3(512/32, 2048/32), 256, 0, stream>>>(w2, w2T, 2048, 512);
    ln_bf16<true><<<MTOK, 256, 0, stream>>>(x1, ln2_g, ln2_b, y, b2, out);
    gemm64<2,true,false,1,false,8><<<dim3(1024,1,1), 256, 0, stream>>>(
        y, w1T, b1, hid, MTOK, 2048, 512, 32);
    gemm64<3,false,false,4,false,8><<<dim3(256,1,4), 256, 0, stream>>>(
        hid, w2T, nullptr, out, MTOK, 512, 2048, 8);
}

// Round 11
// 111.973 us; speedup vs baseline: 1.2280x; 1.0065x over previous
//
#include <hip/hip_runtime.h>
#include <hip/hip_bf16.h>
#include <math.h>

#define NHEADS 8
#define NTOK   1024
#define MTOK   2048

typedef __attribute__((ext_vector_type(8))) short  sh8;
typedef __attribute__((ext_vector_type(8))) __bf16 bf16x8;
typedef __attribute__((ext_vector_type(4))) float  f32x4;
typedef __attribute__((ext_vector_type(4))) unsigned int u32x4;

__device__ __forceinline__ short f2bf(float v) {
    return __builtin_bit_cast(short, __float2bfloat16(v));
}
__device__ __forceinline__ float bf2f(short v) {
    return __builtin_bit_cast(float, ((unsigned)(unsigned short)v) << 16);
}
__device__ __forceinline__ float ex2(float v) {
    return __builtin_amdgcn_exp2f(v);
}
__device__ __forceinline__ f32x4 mfma16(sh8 a, sh8 b, f32x4 c) {
    return __builtin_amdgcn_mfma_f32_16x16x32_bf16(
        __builtin_bit_cast(bf16x8, a), __builtin_bit_cast(bf16x8, b), c, 0, 0, 0);
}
__device__ __forceinline__ void aload16(void* lds, const void* g) {
    __builtin_amdgcn_global_load_lds(
        (const __attribute__((address_space(1))) unsigned int*)g,
        (__attribute__((address_space(3))) unsigned int*)lds, 16, 0, 0);
}

#define LOG2E 1.4426950408889634f

// ---------------- LayerNorm -> bf16 (optionally fuse resout = x + bias2) -------
template<bool FUSE>
__global__ __launch_bounds__(256) void ln_bf16(const float* __restrict__ x,
    const float* __restrict__ g, const float* __restrict__ bta, short* __restrict__ y,
    const float* __restrict__ bias2, float* __restrict__ resout)
{
    int row = blockIdx.x, t = threadIdx.x;
    const float* xr = x + (size_t)row * 512;
    float2 v = *reinterpret_cast<const float2*>(&xr[t*2]);
    float s = v.x + v.y, ss = v.x*v.x + v.y*v.y;
    #pragma unroll
    for (int m = 1; m < 64; m <<= 1) { s += __shfl_xor(s, m); ss += __shfl_xor(ss, m); }
    __shared__ float red[8];
    int wid = t >> 6, lane = t & 63;
    if (!lane) { red[wid] = s; red[4+wid] = ss; }
    __syncthreads();
    s = red[0]+red[1]+red[2]+red[3]; ss = red[4]+red[5]+red[6]+red[7];
    float mu = s*(1.f/512), var = ss*(1.f/512) - mu*mu, rs = rsqrtf(var + 1e-5f);
    float2 gg = *reinterpret_cast<const float2*>(&g[t*2]);
    float2 bb = *reinterpret_cast<const float2*>(&bta[t*2]);
    short2 o; o.x = f2bf((v.x-mu)*rs*gg.x + bb.x); o.y = f2bf((v.y-mu)*rs*gg.y + bb.y);
    *reinterpret_cast<short2*>(&y[(size_t)row*512 + t*2]) = o;
    if (FUSE) {
        float2 b2 = *reinterpret_cast<const float2*>(&bias2[t*2]);
        float2 ro = {v.x + b2.x, v.y + b2.y};
        *reinterpret_cast<float2*>(&resout[(size_t)row*512 + t*2]) = ro;
    }
}

// ---------------- fp32 W[K][N] -> bf16 W^T[N][K] ----------------
__global__ __launch_bounds__(256) void wconv_t(const float* __restrict__ W,
    short* __restrict__ WT, int K, int N)
{
    __shared__ float t[32][33];
    int bn = blockIdx.x * 32, bk = blockIdx.y * 32;
    int c = threadIdx.x & 31, r8 = threadIdx.x >> 5;
    #pragma unroll
    for (int i = 0; i < 4; ++i) {
        int r = r8 + i*8;
        t[r][c] = W[(size_t)(bk + r)*N + bn + c];
    }
    __syncthreads();
    #pragma unroll
    for (int i = 0; i < 4; ++i) {
        int r = r8 + i*8;
        WT[(size_t)(bn + r)*K + bk + c] = f2bf(t[c][r]);
    }
}

// ---------------- pack padding mask into per-(row, 64-tile) bit masks ----------
__global__ __launch_bounds__(256) void mask_pack(const unsigned char* __restrict__ m,
    unsigned long long* __restrict__ mb)
{
    int gw = blockIdx.x*4 + (threadIdx.x >> 6);   // 32768 waves
    int row = gw >> 4, jt = gw & 15, j = threadIdx.x & 63;
    unsigned char v = m[(size_t)row*NTOK + jt*64 + j];
    unsigned long long bits = __ballot(v != 0);
    if (j == 0) mb[(size_t)row*16 + jt] = bits;
}

// ---------------- rn[b*1024+j][i] = |c[b,i]-c[b,j]| as bf16 (symmetric) --------
__global__ __launch_bounds__(256) void rn_pre(const float* __restrict__ coords,
    short* __restrict__ rnT)
{
    int row = blockIdx.x;                    // b*1024 + j
    int b = row >> 10;
    float2 cj = *reinterpret_cast<const float2*>(&coords[(size_t)row*2]);
    int i0 = threadIdx.x * 4;
    float4 a = *reinterpret_cast<const float4*>(&coords[(size_t)(b*1024 + i0)*2]);
    float4 d = *reinterpret_cast<const float4*>(&coords[(size_t)(b*1024 + i0 + 2)*2]);
    short4 o;
    o.x = f2bf(sqrtf((a.x-cj.x)*(a.x-cj.x) + (a.y-cj.y)*(a.y-cj.y)));
    o.y = f2bf(sqrtf((a.z-cj.x)*(a.z-cj.x) + (a.w-cj.y)*(a.w-cj.y)));
    o.z = f2bf(sqrtf((d.x-cj.x)*(d.x-cj.x) + (d.y-cj.y)*(d.y-cj.y)));
    o.w = f2bf(sqrtf((d.z-cj.x)*(d.z-cj.x) + (d.w-cj.y)*(d.w-cj.y)));
    *reinterpret_cast<short4*>(&rnT[(size_t)row*1024 + i0]) = o;
}

// ---------------- bf16 MFMA GEMM, 64x64 tile, BK=64, 3-stage counted-vmcnt ----
template<int EPI, bool OUTBF, bool BIAS_ROW, int SPLITK, bool QSC, int NT>
__global__ __launch_bounds__(256) void gemm64(
    const short* __restrict__ A, const short* __restrict__ BT,
    const float* __restrict__ bias, void* __restrict__ Cout,
    int M, int N, int K, int nbx)
{
    __shared__ sh8 As8[3][512];
    __shared__ sh8 Bs8[3][512];
    int tid = threadIdx.x;
    int w = tid >> 6, lane = tid & 63, lr = lane & 15, lg = lane >> 4;
    int wr = w >> 1, wc = w & 1;
    int cpx = gridDim.x >> 3;
    int swz = (blockIdx.x & 7)*cpx + (blockIdx.x >> 3);
    int bx = swz % nbx, by = swz / nbx;
    int bm0 = by*64, bn0 = bx*64;
    int kbeg = (K / SPLITK) * blockIdx.z;

    f32x4 zero = {0.f,0.f,0.f,0.f};
    f32x4 acc[2][2];
    #pragma unroll
    for (int m = 0; m < 2; ++m)
        #pragma unroll
        for (int n = 0; n < 2; ++n) acc[m][n] = zero;

    #define STAGE(buf, k0) { \
        _Pragma("unroll") \
        for (int it = 0; it < 2; ++it) { \
            int s = tid + it*256; \
            int r = s >> 3, g = s & 7; \
            int ksw = (k0) + ((g ^ (r & 7)) << 3); \
            aload16(&As8[buf][s], A  + (size_t)(bm0 + r)*K + ksw); \
            aload16(&Bs8[buf][s], BT + (size_t)(bn0 + r)*K + ksw); \
        } }

    STAGE(0, kbeg)
    if (NT > 1) STAGE(1, kbeg + 64)

    #pragma unroll
    for (int t = 0; t < NT; ++t) {
        if (t + 1 < NT) asm volatile("s_waitcnt vmcnt(4)" ::: "memory");
        else            asm volatile("s_waitcnt vmcnt(0)" ::: "memory");
        __builtin_amdgcn_s_barrier();
        __builtin_amdgcn_sched_barrier(0);
        int buf = t % 3;
        sh8 af[2][2], bfv[2][2];
        #pragma unroll
        for (int m = 0; m < 2; ++m) {
            int R = wr*32 + m*16 + lr;
            #pragma unroll
            for (int s = 0; s < 2; ++s) af[m][s] = As8[buf][R*8 + ((s*4+lg) ^ (R & 7))];
        }
        #pragma unroll
        for (int n = 0; n < 2; ++n) {
            int R = wc*32 + n*16 + lr;
            #pragma unroll
            for (int s = 0; s < 2; ++s) bfv[n][s] = Bs8[buf][R*8 + ((s*4+lg) ^ (R & 7))];
        }
        if (t + 2 < NT) STAGE((t+2)%3, kbeg + (t+2)*64)
        #pragma unroll
        for (int m = 0; m < 2; ++m)
            #pragma unroll
            for (int n = 0; n < 2; ++n)
                #pragma unroll
                for (int s = 0; s < 2; ++s)
                    acc[m][n] = mfma16(af[m][s], bfv[n][s], acc[m][n]);
        asm volatile("s_waitcnt lgkmcnt(0)" ::: "memory");
    }
    #undef STAGE

    #pragma unroll
    for (int m = 0; m < 2; ++m) {
        #pragma unroll
        for (int n = 0; n < 2; ++n) {
            #pragma unroll
            for (int r = 0; r < 4; ++r) {
                int row = bm0 + wr*32 + m*16 + lg*4 + r;
                int col = bn0 + wc*32 + n*16 + lr;
                if (EPI == 3) {
                    atomicAdd((float*)Cout + (size_t)row*N + col, acc[m][n][r]);
                } else {
                    float v = acc[m][n][r] + (BIAS_ROW ? bias[row] : bias[col]);
                    if (QSC && col < 512) v *= (0.125f * LOG2E);
                    if (EPI == 2) v = 0.5f * v * (1.0f + erff(v * 0.70710678f));
                    if (OUTBF) ((short*)Cout)[(size_t)row*N + col] = f2bf(v);
                    else       ((float*)Cout)[(size_t)row*N + col] = v;
                }
            }
        }
    }
}

// ---------------- LDS-staged MFMA flash attention, KV-split x4, swapped QK ----
// S^T = mfma(K, Q): each lane owns one q-row (q=lr) and 16 k's -> softmax is
// lane-local (2 shfls). P stays in registers; PA fragments built via 8 shfls.
// No P LDS roundtrip, 1 mask load/lane/tile.
__global__ __launch_bounds__(256) void attn_reg(
    const short* __restrict__ qk, const short* __restrict__ vt,
    const short* __restrict__ rnT, const unsigned long long* __restrict__ mb64,
    const float* __restrict__ w_edge, short* __restrict__ OpA,
    short* __restrict__ OpB, float* __restrict__ ml)
{
    __shared__ sh8 Ks8[2][512];   // [64 k][8 slots 16B] swizzled
    __shared__ sh8 Vs8[2][512];   // [64 d][8 slots 16B] swizzled

    int cpx = gridDim.x >> 3;     // 1024 blocks -> 128
    int swz = (blockIdx.x & 7)*cpx + (blockIdx.x >> 3);
    int w = threadIdx.x >> 6, lane = threadIdx.x & 63;
    int lr = lane & 15, lg = lane >> 4;
    int qb = swz & 15;            // q block of 64 rows
    int h  = (swz >> 4) & 7;
    int b  = (swz >> 7) & 1;
    int ks = swz >> 8;            // KV split 0..3

    const int q0 = qb*64 + w*16;
    const int qrow0 = b*NTOK + q0;
    const int jt0 = ks*4;

    sh8 qf[2];   // Q[q=lr][d=s*32+lg*8..] — serves as the MFMA B operand
    #pragma unroll
    for (int s = 0; s < 2; ++s)
        qf[s] = *reinterpret_cast<const sh8*>(qk + (size_t)(qrow0 + lr)*1024 + h*64 + s*32 + lg*8);

    float we2l = w_edge[2*NHEADS + h] * LOG2E;

    float m_i = -1e30f, l_lane = 0.f;   // per-lane: stats for q = lr
    f32x4 zero = {0.f,0.f,0.f,0.f};
    f32x4 accO[4];
    #pragma unroll
    for (int n = 0; n < 4; ++n) accO[n] = zero;

    const short* kbase = qk + 512 + h*64;
    const short* vbase = vt + (size_t)h*64*2048 + b*NTOK;
    int sr = threadIdx.x >> 3, sg = threadIdx.x & 7;
    int sx = (sg ^ (sr & 7)) << 3;

    #define ASTAGE(bf, jt) { \
        aload16(&Ks8[bf][threadIdx.x],       kbase + (size_t)(b*NTOK + (jt)*64 + sr)*1024 + sx); \
        aload16(&Ks8[bf][threadIdx.x + 256], kbase + (size_t)(b*NTOK + (jt)*64 + sr + 32)*1024 + sx); \
        aload16(&Vs8[bf][threadIdx.x],       vbase + (size_t)sr*2048 + (jt)*64 + sx); \
        aload16(&Vs8[bf][threadIdx.x + 256], vbase + (size_t)(sr + 32)*2048 + (jt)*64 + sx); \
    }

    // rn: lane needs rn[q=q0+lr][jt*64 + n*16 + lg*4 + r] (table is symmetric)
    short4 rn_reg[2][4];
    unsigned long long mr_reg[2];
    #define RMLOAD(bf, jt) { \
        _Pragma("unroll") \
        for (int n = 0; n < 4; ++n) \
            rn_reg[bf][n] = *reinterpret_cast<const short4*>( \
                &rnT[(size_t)(b*1024 + q0 + lr)*1024 + (jt)*64 + n*16 + lg*4]); \
        mr_reg[bf] = mb64[(size_t)(qrow0 + lr)*16 + (jt)]; \
    }

    ASTAGE(0, jt0)
    RMLOAD(0, jt0)

    #pragma unroll
    for (int t = 0; t < 4; ++t) {
        if (t == 0) asm volatile("s_waitcnt vmcnt(0)" ::: "memory");
        else        asm volatile("s_waitcnt vmcnt(5)" ::: "memory");
        __builtin_amdgcn_s_barrier();
        __builtin_amdgcn_sched_barrier(0);
        int buf = t & 1;

        if (t + 1 < 4) {
            ASTAGE(buf ^ 1, jt0 + t + 1)
            RMLOAD(buf ^ 1, jt0 + t + 1)
        }

        // S^T = K Q^T: lane holds S[k = 16n + 4lg + r][q = lr]
        f32x4 Sv[4];
        #pragma unroll
        for (int n = 0; n < 4; ++n) {
            int kcol = n*16 + lr;
            sh8 k0v = Ks8[buf][kcol*8 + (lg       ^ (kcol & 7))];
            sh8 k1v = Ks8[buf][kcol*8 + ((4 + lg) ^ (kcol & 7))];
            Sv[n] = mfma16(k1v, qf[1], mfma16(k0v, qf[0], zero));
        }

        // radial bias (log2 domain)
        #pragma unroll
        for (int n = 0; n < 4; ++n) {
            short4 rn4 = rn_reg[buf][n];
            Sv[n][0] = fmaf(bf2f(rn4.x), we2l, Sv[n][0]);
            Sv[n][1] = fmaf(bf2f(rn4.y), we2l, Sv[n][1]);
            Sv[n][2] = fmaf(bf2f(rn4.z), we2l, Sv[n][2]);
            Sv[n][3] = fmaf(bf2f(rn4.w), we2l, Sv[n][3]);
        }

        // lane-local max over 16 + 2-shfl row reduce (across lg groups)
        float mx = Sv[0][0];
        #pragma unroll
        for (int n = 0; n < 4; ++n)
            #pragma unroll
            for (int r = 0; r < 4; ++r) mx = fmaxf(mx, Sv[n][r]);
        mx = fmaxf(mx, __shfl_xor(mx, 16));
        mx = fmaxf(mx, __shfl_xor(mx, 32));
        float mnew = fmaxf(m_i, mx);
        float f = ex2(m_i - mnew);
        m_i = mnew;

        // exp, mask-zero (post-exp), lane-partial sum, pack to bf16 pairs
        unsigned long long mr = mr_reg[buf];
        float ps = 0.f;
        unsigned pk[8];
        #pragma unroll
        for (int n = 0; n < 4; ++n) {
            float p_[4];
            #pragma unroll
            for (int r = 0; r < 4; ++r) {
                float p = ex2(Sv[n][r] - mnew);
                p = ((mr >> (n*16 + lg*4 + r)) & 1ull) ? 0.f : p;
                ps += p;
                p_[r] = p;
            }
            pk[2*n]   = ((unsigned)(unsigned short)f2bf(p_[1]) << 16) | (unsigned short)f2bf(p_[0]);
            pk[2*n+1] = ((unsigned)(unsigned short)f2bf(p_[3]) << 16) | (unsigned short)f2bf(p_[2]);
        }
        l_lane = l_lane * f + ps;

        // build PA fragments (A operand: row q=lr, k = s*32 + lg*8 + j) via shfl
        int src0 = lr + ((lg & 1) << 5);    // m0 = 2*(lg&1) -> lane lr + 16*m0
        int src1 = src0 + 16;
        sh8 pa[2];
        #pragma unroll
        for (int s = 0; s < 2; ++s) {
            int ns = 2*s + (lg >> 1);
            u32x4 dv;
            dv.x = (unsigned)__shfl((int)pk[2*ns],   src0);
            dv.y = (unsigned)__shfl((int)pk[2*ns+1], src0);
            dv.z = (unsigned)__shfl((int)pk[2*ns],   src1);
            dv.w = (unsigned)__shfl((int)pk[2*ns+1], src1);
            pa[s] = __builtin_bit_cast(sh8, dv);
        }

        // broadcast rescale factor into accO layout (row q = lg*4 + r)
        float fb[4];
        #pragma unroll
        for (int r = 0; r < 4; ++r) fb[r] = __shfl(f, lg*4 + r);
        #pragma unroll
        for (int n = 0; n < 4; ++n)
            #pragma unroll
            for (int r = 0; r < 4; ++r) accO[n][r] *= fb[r];

        // PV: O[q][d], V frags from LDS
        #pragma unroll
        for (int n = 0; n < 4; ++n) {
            int dcol = n*16 + lr;
            sh8 v0 = Vs8[buf][dcol*8 + (lg       ^ (dcol & 7))];
            sh8 v1 = Vs8[buf][dcol*8 + ((4 + lg) ^ (dcol & 7))];
            accO[n] = mfma16(pa[1], v1, mfma16(pa[0], v0, accO[n]));
        }

        asm volatile("s_waitcnt lgkmcnt(0)" ::: "memory");
    }
    #undef ASTAGE
    #undef RMLOAD

    // final l: sum lane-partials across lg groups
    l_lane += __shfl_xor(l_lane, 16);
    l_lane += __shfl_xor(l_lane, 32);

    // partials: unnormalized bf16 O + (m, l); splits {0,1}->OpA, {2,3}->OpB
    short* Op = (ks < 2) ? OpA : OpB;
    #pragma unroll
    for (int r = 0; r < 4; ++r) {
        size_t row = (size_t)((ks & 1)*MTOK + qrow0 + lg*4 + r);
        #pragma unroll
        for (int n = 0; n < 4; ++n)
            Op[row*512 + h*64 + n*16 + lr] = f2bf(accO[n][r]);
    }
    if (lg == 0) {
        size_t mrow = (size_t)(ks*MTOK + qrow0 + lr);
        ml[(mrow*NHEADS + h)*2 + 0] = m_i;
        ml[(mrow*NHEADS + h)*2 + 1] = l_lane;
    }
}

// ---------------- combine 4 KV-split partials -> bf16 O; fuse x1 = x + b_out --
__global__ __launch_bounds__(256) void attn_combine4(const short* __restrict__ OpA,
    const short* __restrict__ OpB, const float* __restrict__ ml,
    short* __restrict__ ob, const float* __restrict__ x,
    const float* __restrict__ b_out, float* __restrict__ x1)
{
    int idx = blockIdx.x*256 + threadIdx.x;     // MTOK*128 threads
    int tok = idx >> 7, dd = (idx & 127) * 4;
    int h = dd >> 6;
    float m[4], l[4];
    #pragma unroll
    for (int s = 0; s < 4; ++s) {
        m[s] = ml[(((size_t)s*MTOK + tok)*NHEADS + h)*2 + 0];
        l[s] = ml[(((size_t)s*MTOK + tok)*NHEADS + h)*2 + 1];
    }
    float mm = fmaxf(fmaxf(m[0], m[1]), fmaxf(m[2], m[3]));
    float wsum = 0.f, a0 = 0.f, a1 = 0.f, a2 = 0.f, a3 = 0.f;
    #pragma unroll
    for (int s = 0; s < 4; ++s) {
        float wv = ex2(m[s] - mm);
        wsum += wv * l[s];
        const short* Op = (s < 2) ? OpA : OpB;
        short4 p = *reinterpret_cast<const short4*>(&Op[((size_t)((s&1)*MTOK) + tok)*512 + dd]);
        a0 += bf2f(p.x)*wv; a1 += bf2f(p.y)*wv;
        a2 += bf2f(p.z)*wv; a3 += bf2f(p.w)*wv;
    }
    float inv = 1.f / wsum;
    short4 o;
    o.x = f2bf(a0*inv); o.y = f2bf(a1*inv);
    o.z = f2bf(a2*inv); o.w = f2bf(a3*inv);
    *reinterpret_cast<short4*>(&ob[(size_t)tok*512 + dd]) = o;
    float4 xv = *reinterpret_cast<const float4*>(&x[(size_t)tok*512 + dd]);
    float4 bv = *reinterpret_cast<const float4*>(&b_out[dd]);
    float4 xo = {xv.x+bv.x, xv.y+bv.y, xv.z+bv.z, xv.w+bv.w};
    *reinterpret_cast<float4*>(&x1[(size_t)tok*512 + dd]) = xo;
}

// -------------------------------------------------------------------------------
extern "C" void kernel_launch(void* const* d_in, const int* in_sizes, int n_in,
                              void* d_out, int out_size, void* d_ws, size_t ws_size,
                              hipStream_t stream)
{
    const float* x      = (const float*)d_in[0];
    const float* coords = (const float*)d_in[1];
    const unsigned char* mask = (const unsigned char*)d_in[2];
    const float* ln1_g = (const float*)d_in[3];
    const float* ln1_b = (const float*)d_in[4];
    const float* w_qkv = (const float*)d_in[5];
    const float* b_qkv = (const float*)d_in[6];
    const float* w_edge= (const float*)d_in[7];
    const float* w_out = (const float*)d_in[8];
    const float* b_out = (const float*)d_in[9];
    const float* ln2_g = (const float*)d_in[10];
    const float* ln2_b = (const float*)d_in[11];
    const float* w1    = (const float*)d_in[12];
    const float* b1    = (const float*)d_in[13];
    const float* w2    = (const float*)d_in[14];
    const float* b2    = (const float*)d_in[15];
    float* out = (float*)d_out;

    char* W = (char*)d_ws;
    const size_t MB = 1024*1024;
    float* x1    = (float*)(W);                    // [0,4M) f32 (written post-attn)
    short* qk    = (short*)(W + 4*MB);             // [4M,8M)
    short* vtb   = (short*)(W + 8*MB);             // [8M,10M)
    short* woutT = (short*)(W + 10*MB);            // [10M,10.5M)
    short* xln   = (short*)(W + 10*MB + 512*1024); // [10.5M,12.5M)  (later y)
    short* wqkvT = (short*)(W + 12*MB + 512*1024); // [12.5M,14M)
    short* OpB   = (short*)(W + 10*MB + 512*1024); // [10.5M,14.5M) over dead xln/wqkvT
    short* OpA   = (short*)(W + 14*MB + 512*1024); // [14.5M,18.5M)
    short* rnT   = (short*)(W + 18*MB + 512*1024); // [18.5M,22.5M) bf16 2048x1024
    float* mlp   = (float*)(W + 22*MB + 512*1024); // [22.5M,23M) 4x2048x8x2 f32
    unsigned long long* mb64 = (unsigned long long*)(W + 23*MB); // [23M,23.25M)
    short* ob    = (short*)(W + 6*MB);             // [6M,8M)  (qk dead after attn)
    short* y     = xln;                            // [10.5M,12.5M) (OpB dead)
    short* w1T   = (short*)(W + 4*MB);             // [4M,6M)  (qk dead)
    short* w2T   = (short*)(W + 8*MB);             // [8M,10M) (vtb dead)
    short* hid   = (short*)(W + 14*MB + 512*1024); // [14.5M,22.5M) (OpA/rnT dead)

    // ---- phase 1 ----
    mask_pack<<<dim3(8192,1,1), 256, 0, stream>>>(mask, mb64);
    rn_pre<<<dim3(2048,1,1), 256, 0, stream>>>(coords, rnT);
    wconv_t<<<dim3(1536/32, 512/32), 256, 0, stream>>>(w_qkv, wqkvT, 512, 1536);
    wconv_t<<<dim3(512/32, 512/32), 256, 0, stream>>>(w_out, woutT, 512, 512);
    ln_bf16<false><<<MTOK, 256, 0, stream>>>(x, ln1_g, ln1_b, xln, nullptr, nullptr);
    gemm64<0,true,false,1,true,8><<<dim3(512,1,1), 256, 0, stream>>>(
        xln, wqkvT, b_qkv, qk, MTOK, 1024, 512, 16);
    gemm64<0,true,true,1,false,8><<<dim3(256,1,1), 256, 0, stream>>>(
        wqkvT + (size_t)1024*512, xln, b_qkv + 1024, vtb, 512, MTOK, 512, 32);
    attn_reg<<<dim3(1024,1,1), 256, 0, stream>>>(qk, vtb, rnT, mb64, w_edge, OpA, OpB, mlp);
    attn_combine4<<<dim3(1024,1,1), 256, 0, stream>>>(OpA, OpB, mlp, ob, x, b_out, x1);
    gemm64<3,false,false,2,false,4><<<dim3(256,1,2), 256, 0, stream>>>(
        ob, woutT, nullptr, x1, MTOK, 512, 512, 8);
    // ---- phase 2 ----
    wconv_t<<<dim3(2048/32, 512/32), 256, 0, stream>>>(w1, w1T, 512, 2048);
    wconv_t<<<dim3(512/32, 2048/32), 256, 0, stream>>>(w2, w2T, 2048, 512);
    ln_bf16<true><<<MTOK, 256, 0, stream>>>(x1, ln2_g, ln2_b, y, b2, out);
    gemm64<2,true,false,1,false,8><<<dim3(1024,1,1), 256, 0, stream>>>(
        y, w1T, b1, hid, MTOK, 2048, 512, 32);
    gemm64<3,false,false,4,false,8><<<dim3(256,1,4), 256, 0, stream>>>(
        hid, w2T, nullptr, out, MTOK, 512, 2048, 8);
}

// Round 12
// 95.463 us; speedup vs baseline: 1.4404x; 1.1729x over previous
//
#include <hip/hip_runtime.h>
#include <hip/hip_bf16.h>
#include <math.h>

#define NHEADS 8
#define NTOK   1024
#define MTOK   2048

typedef __attribute__((ext_vector_type(8))) short  sh8;
typedef __attribute__((ext_vector_type(8))) __bf16 bf16x8;
typedef __attribute__((ext_vector_type(4))) float  f32x4;
typedef __attribute__((ext_vector_type(4))) unsigned int u32x4;

__device__ __forceinline__ short f2bf(float v) {
    return __builtin_bit_cast(short, __float2bfloat16(v));
}
__device__ __forceinline__ float bf2f(short v) {
    return __builtin_bit_cast(float, ((unsigned)(unsigned short)v) << 16);
}
__device__ __forceinline__ float ex2(float v) {
    return __builtin_amdgcn_exp2f(v);
}
__device__ __forceinline__ f32x4 mfma16(sh8 a, sh8 b, f32x4 c) {
    return __builtin_amdgcn_mfma_f32_16x16x32_bf16(
        __builtin_bit_cast(bf16x8, a), __builtin_bit_cast(bf16x8, b), c, 0, 0, 0);
}
__device__ __forceinline__ void aload16(void* lds, const void* g) {
    __builtin_amdgcn_global_load_lds(
        (const __attribute__((address_space(1))) unsigned int*)g,
        (__attribute__((address_space(3))) unsigned int*)lds, 16, 0, 0);
}

#define LOG2E 1.4426950408889634f

// ---------------- LayerNorm -> bf16 (optionally fuse resout = x + bias2) -------
template<bool FUSE>
__global__ __launch_bounds__(256) void ln_bf16(const float* __restrict__ x,
    const float* __restrict__ g, const float* __restrict__ bta, short* __restrict__ y,
    const float* __restrict__ bias2, float* __restrict__ resout)
{
    int row = blockIdx.x, t = threadIdx.x;
    const float* xr = x + (size_t)row * 512;
    float2 v = *reinterpret_cast<const float2*>(&xr[t*2]);
    float s = v.x + v.y, ss = v.x*v.x + v.y*v.y;
    #pragma unroll
    for (int m = 1; m < 64; m <<= 1) { s += __shfl_xor(s, m); ss += __shfl_xor(ss, m); }
    __shared__ float red[8];
    int wid = t >> 6, lane = t & 63;
    if (!lane) { red[wid] = s; red[4+wid] = ss; }
    __syncthreads();
    s = red[0]+red[1]+red[2]+red[3]; ss = red[4]+red[5]+red[6]+red[7];
    float mu = s*(1.f/512), var = ss*(1.f/512) - mu*mu, rs = rsqrtf(var + 1e-5f);
    float2 gg = *reinterpret_cast<const float2*>(&g[t*2]);
    float2 bb = *reinterpret_cast<const float2*>(&bta[t*2]);
    short2 o; o.x = f2bf((v.x-mu)*rs*gg.x + bb.x); o.y = f2bf((v.y-mu)*rs*gg.y + bb.y);
    *reinterpret_cast<short2*>(&y[(size_t)row*512 + t*2]) = o;
    if (FUSE) {
        float2 b2 = *reinterpret_cast<const float2*>(&bias2[t*2]);
        float2 ro = {v.x + b2.x, v.y + b2.y};
        *reinterpret_cast<float2*>(&resout[(size_t)row*512 + t*2]) = ro;
    }
}

// ---------------- merged: two fp32 W[K][N] -> bf16 W^T[N][K] transposes --------
__global__ __launch_bounds__(256) void wconv2x(
    const float* __restrict__ W0, short* __restrict__ WT0, int K0, int N0, int nb0,
    const float* __restrict__ W1, short* __restrict__ WT1, int K1, int N1)
{
    const float* W; short* WT; int K, N, bid;
    if ((int)blockIdx.x < nb0) { W = W0; WT = WT0; K = K0; N = N0; bid = blockIdx.x; }
    else                       { W = W1; WT = WT1; K = K1; N = N1; bid = blockIdx.x - nb0; }
    int nbx = N >> 5;
    int bn = (bid % nbx) * 32, bk = (bid / nbx) * 32;
    __shared__ float t[32][33];
    int c = threadIdx.x & 31, r8 = threadIdx.x >> 5;
    #pragma unroll
    for (int i = 0; i < 4; ++i) {
        int r = r8 + i*8;
        t[r][c] = W[(size_t)(bk + r)*N + bn + c];
    }
    __syncthreads();
    #pragma unroll
    for (int i = 0; i < 4; ++i) {
        int r = r8 + i*8;
        WT[(size_t)(bn + r)*K + bk + c] = f2bf(t[c][r]);
    }
}

// ---------------- prep: rn table + mask bit-pack, one block per (b*1024+j) row --
__global__ __launch_bounds__(256) void prep(const float* __restrict__ coords,
    const unsigned char* __restrict__ mask, short* __restrict__ rnT,
    unsigned long long* __restrict__ mb)
{
    int row = blockIdx.x;                    // b*1024 + j
    int b = row >> 10;
    float2 cj = *reinterpret_cast<const float2*>(&coords[(size_t)row*2]);
    int i0 = threadIdx.x * 4;
    float4 a = *reinterpret_cast<const float4*>(&coords[(size_t)(b*1024 + i0)*2]);
    float4 d = *reinterpret_cast<const float4*>(&coords[(size_t)(b*1024 + i0 + 2)*2]);
    short4 o;
    o.x = f2bf(sqrtf((a.x-cj.x)*(a.x-cj.x) + (a.y-cj.y)*(a.y-cj.y)));
    o.y = f2bf(sqrtf((a.z-cj.x)*(a.z-cj.x) + (a.w-cj.y)*(a.w-cj.y)));
    o.z = f2bf(sqrtf((d.x-cj.x)*(d.x-cj.x) + (d.y-cj.y)*(d.y-cj.y)));
    o.w = f2bf(sqrtf((d.z-cj.x)*(d.z-cj.x) + (d.w-cj.y)*(d.w-cj.y)));
    *reinterpret_cast<short4*>(&rnT[(size_t)row*1024 + i0]) = o;

    // mask bit-pack: wave w covers tiles i*4 + w (64 cols each)
    int w = threadIdx.x >> 6, lane = threadIdx.x & 63;
    #pragma unroll
    for (int i = 0; i < 4; ++i) {
        unsigned char v = mask[(size_t)row*NTOK + i*256 + w*64 + lane];
        unsigned long long bits = __ballot(v != 0);
        if (!lane) mb[(size_t)row*16 + i*4 + w] = bits;
    }
}

// ---------------- bf16 MFMA GEMM, 64x64 tile, BK=64, 3-stage counted-vmcnt ----
// EPI: 0 bias; 1 bias+res (f32 out); 2 bias+gelu; 3 split-K atomicAdd (f32)
template<int EPI, bool OUTBF, bool BIAS_ROW, int SPLITK, bool QSC, int NT>
__global__ __launch_bounds__(256) void gemm64(
    const short* __restrict__ A, const short* __restrict__ BT,
    const float* __restrict__ bias, const float* __restrict__ res,
    void* __restrict__ Cout, int M, int N, int K, int nbx)
{
    __shared__ sh8 As8[3][512];
    __shared__ sh8 Bs8[3][512];
    int tid = threadIdx.x;
    int w = tid >> 6, lane = tid & 63, lr = lane & 15, lg = lane >> 4;
    int wr = w >> 1, wc = w & 1;
    int cpx = gridDim.x >> 3;
    int swz = (blockIdx.x & 7)*cpx + (blockIdx.x >> 3);
    int bx = swz % nbx, by = swz / nbx;
    int bm0 = by*64, bn0 = bx*64;
    int kbeg = (K / SPLITK) * blockIdx.z;

    f32x4 zero = {0.f,0.f,0.f,0.f};
    f32x4 acc[2][2];
    #pragma unroll
    for (int m = 0; m < 2; ++m)
        #pragma unroll
        for (int n = 0; n < 2; ++n) acc[m][n] = zero;

    #define STAGE(buf, k0) { \
        _Pragma("unroll") \
        for (int it = 0; it < 2; ++it) { \
            int s = tid + it*256; \
            int r = s >> 3, g = s & 7; \
            int ksw = (k0) + ((g ^ (r & 7)) << 3); \
            aload16(&As8[buf][s], A  + (size_t)(bm0 + r)*K + ksw); \
            aload16(&Bs8[buf][s], BT + (size_t)(bn0 + r)*K + ksw); \
        } }

    STAGE(0, kbeg)
    if (NT > 1) STAGE(1, kbeg + 64)

    #pragma unroll
    for (int t = 0; t < NT; ++t) {
        if (t + 1 < NT) asm volatile("s_waitcnt vmcnt(4)" ::: "memory");
        else            asm volatile("s_waitcnt vmcnt(0)" ::: "memory");
        __builtin_amdgcn_s_barrier();
        __builtin_amdgcn_sched_barrier(0);
        int buf = t % 3;
        sh8 af[2][2], bfv[2][2];
        #pragma unroll
        for (int m = 0; m < 2; ++m) {
            int R = wr*32 + m*16 + lr;
            #pragma unroll
            for (int s = 0; s < 2; ++s) af[m][s] = As8[buf][R*8 + ((s*4+lg) ^ (R & 7))];
        }
        #pragma unroll
        for (int n = 0; n < 2; ++n) {
            int R = wc*32 + n*16 + lr;
            #pragma unroll
            for (int s = 0; s < 2; ++s) bfv[n][s] = Bs8[buf][R*8 + ((s*4+lg) ^ (R & 7))];
        }
        if (t + 2 < NT) STAGE((t+2)%3, kbeg + (t+2)*64)
        #pragma unroll
        for (int m = 0; m < 2; ++m)
            #pragma unroll
            for (int n = 0; n < 2; ++n)
                #pragma unroll
                for (int s = 0; s < 2; ++s)
                    acc[m][n] = mfma16(af[m][s], bfv[n][s], acc[m][n]);
        asm volatile("s_waitcnt lgkmcnt(0)" ::: "memory");
    }
    #undef STAGE

    #pragma unroll
    for (int m = 0; m < 2; ++m) {
        #pragma unroll
        for (int n = 0; n < 2; ++n) {
            #pragma unroll
            for (int r = 0; r < 4; ++r) {
                int row = bm0 + wr*32 + m*16 + lg*4 + r;
                int col = bn0 + wc*32 + n*16 + lr;
                if (EPI == 3) {
                    atomicAdd((float*)Cout + (size_t)row*N + col, acc[m][n][r]);
                } else {
                    float v = acc[m][n][r] + (BIAS_ROW ? bias[row] : bias[col]);
                    if (QSC && col < 512) v *= (0.125f * LOG2E);
                    if (EPI == 1) v += res[(size_t)row*N + col];
                    if (EPI == 2) v = 0.5f * v * (1.0f + erff(v * 0.70710678f));
                    if (OUTBF) ((short*)Cout)[(size_t)row*N + col] = f2bf(v);
                    else       ((float*)Cout)[(size_t)row*N + col] = v;
                }
            }
        }
    }
}

// ---------------- LDS-staged MFMA flash attention, KV-split x4, swapped QK ----
__global__ __launch_bounds__(256) void attn_reg(
    const short* __restrict__ qk, const short* __restrict__ vt,
    const short* __restrict__ rnT, const unsigned long long* __restrict__ mb64,
    const float* __restrict__ w_edge, short* __restrict__ OpA,
    short* __restrict__ OpB, float* __restrict__ ml)
{
    __shared__ sh8 Ks8[2][512];   // [64 k][8 slots 16B] swizzled
    __shared__ sh8 Vs8[2][512];   // [64 d][8 slots 16B] swizzled

    int cpx = gridDim.x >> 3;     // 1024 blocks -> 128
    int swz = (blockIdx.x & 7)*cpx + (blockIdx.x >> 3);
    int w = threadIdx.x >> 6, lane = threadIdx.x & 63;
    int lr = lane & 15, lg = lane >> 4;
    int qb = swz & 15;            // q block of 64 rows
    int h  = (swz >> 4) & 7;
    int b  = (swz >> 7) & 1;
    int ks = swz >> 8;            // KV split 0..3

    const int q0 = qb*64 + w*16;
    const int qrow0 = b*NTOK + q0;
    const int jt0 = ks*4;

    sh8 qf[2];   // Q[q=lr][d=s*32+lg*8..] — MFMA B operand
    #pragma unroll
    for (int s = 0; s < 2; ++s)
        qf[s] = *reinterpret_cast<const sh8*>(qk + (size_t)(qrow0 + lr)*1024 + h*64 + s*32 + lg*8);

    float we2l = w_edge[2*NHEADS + h] * LOG2E;

    float m_i = -1e30f, l_lane = 0.f;   // per-lane: stats for q = lr
    f32x4 zero = {0.f,0.f,0.f,0.f};
    f32x4 accO[4];
    #pragma unroll
    for (int n = 0; n < 4; ++n) accO[n] = zero;

    const short* kbase = qk + 512 + h*64;
    const short* vbase = vt + (size_t)h*64*2048 + b*NTOK;
    int sr = threadIdx.x >> 3, sg = threadIdx.x & 7;
    int sx = (sg ^ (sr & 7)) << 3;

    #define ASTAGE(bf, jt) { \
        aload16(&Ks8[bf][threadIdx.x],       kbase + (size_t)(b*NTOK + (jt)*64 + sr)*1024 + sx); \
        aload16(&Ks8[bf][threadIdx.x + 256], kbase + (size_t)(b*NTOK + (jt)*64 + sr + 32)*1024 + sx); \
        aload16(&Vs8[bf][threadIdx.x],       vbase + (size_t)sr*2048 + (jt)*64 + sx); \
        aload16(&Vs8[bf][threadIdx.x + 256], vbase + (size_t)(sr + 32)*2048 + (jt)*64 + sx); \
    }

    short4 rn_reg[2][4];
    unsigned long long mr_reg[2];
    #define RMLOAD(bf, jt) { \
        _Pragma("unroll") \
        for (int n = 0; n < 4; ++n) \
            rn_reg[bf][n] = *reinterpret_cast<const short4*>( \
                &rnT[(size_t)(b*1024 + q0 + lr)*1024 + (jt)*64 + n*16 + lg*4]); \
        mr_reg[bf] = mb64[(size_t)(qrow0 + lr)*16 + (jt)]; \
    }

    ASTAGE(0, jt0)
    RMLOAD(0, jt0)

    #pragma unroll
    for (int t = 0; t < 4; ++t) {
        if (t == 0) asm volatile("s_waitcnt vmcnt(0)" ::: "memory");
        else        asm volatile("s_waitcnt vmcnt(5)" ::: "memory");
        __builtin_amdgcn_s_barrier();
        __builtin_amdgcn_sched_barrier(0);
        int buf = t & 1;

        if (t + 1 < 4) {
            ASTAGE(buf ^ 1, jt0 + t + 1)
            RMLOAD(buf ^ 1, jt0 + t + 1)
        }

        // S^T = K Q^T: lane holds S[k = 16n + 4lg + r][q = lr]
        f32x4 Sv[4];
        #pragma unroll
        for (int n = 0; n < 4; ++n) {
            int kcol = n*16 + lr;
            sh8 k0v = Ks8[buf][kcol*8 + (lg       ^ (kcol & 7))];
            sh8 k1v = Ks8[buf][kcol*8 + ((4 + lg) ^ (kcol & 7))];
            Sv[n] = mfma16(k1v, qf[1], mfma16(k0v, qf[0], zero));
        }

        // radial bias (log2 domain)
        #pragma unroll
        for (int n = 0; n < 4; ++n) {
            short4 rn4 = rn_reg[buf][n];
            Sv[n][0] = fmaf(bf2f(rn4.x), we2l, Sv[n][0]);
            Sv[n][1] = fmaf(bf2f(rn4.y), we2l, Sv[n][1]);
            Sv[n][2] = fmaf(bf2f(rn4.z), we2l, Sv[n][2]);
            Sv[n][3] = fmaf(bf2f(rn4.w), we2l, Sv[n][3]);
        }

        // lane-local max + 2-shfl reduce
        float mx = Sv[0][0];
        #pragma unroll
        for (int n = 0; n < 4; ++n)
            #pragma unroll
            for (int r = 0; r < 4; ++r) mx = fmaxf(mx, Sv[n][r]);
        mx = fmaxf(mx, __shfl_xor(mx, 16));
        mx = fmaxf(mx, __shfl_xor(mx, 32));
        float mnew = fmaxf(m_i, mx);
        float f = ex2(m_i - mnew);
        m_i = mnew;

        // exp, post-exp mask-zero, lane-partial sum, bf16 pack
        unsigned long long mr = mr_reg[buf];
        float ps = 0.f;
        unsigned pk[8];
        #pragma unroll
        for (int n = 0; n < 4; ++n) {
            float p_[4];
            #pragma unroll
            for (int r = 0; r < 4; ++r) {
                float p = ex2(Sv[n][r] - mnew);
                p = ((mr >> (n*16 + lg*4 + r)) & 1ull) ? 0.f : p;
                ps += p;
                p_[r] = p;
            }
            pk[2*n]   = ((unsigned)(unsigned short)f2bf(p_[1]) << 16) | (unsigned short)f2bf(p_[0]);
            pk[2*n+1] = ((unsigned)(unsigned short)f2bf(p_[3]) << 16) | (unsigned short)f2bf(p_[2]);
        }
        l_lane = l_lane * f + ps;

        // PA fragments via shfl
        int src0 = lr + ((lg & 1) << 5);
        int src1 = src0 + 16;
        sh8 pa[2];
        #pragma unroll
        for (int s = 0; s < 2; ++s) {
            int ns = 2*s + (lg >> 1);
            u32x4 dv;
            dv.x = (unsigned)__shfl((int)pk[2*ns],   src0);
            dv.y = (unsigned)__shfl((int)pk[2*ns+1], src0);
            dv.z = (unsigned)__shfl((int)pk[2*ns],   src1);
            dv.w = (unsigned)__shfl((int)pk[2*ns+1], src1);
            pa[s] = __builtin_bit_cast(sh8, dv);
        }

        // broadcast rescale into accO layout
        float fb[4];
        #pragma unroll
        for (int r = 0; r < 4; ++r) fb[r] = __shfl(f, lg*4 + r);
        #pragma unroll
        for (int n = 0; n < 4; ++n)
            #pragma unroll
            for (int r = 0; r < 4; ++r) accO[n][r] *= fb[r];

        // PV
        #pragma unroll
        for (int n = 0; n < 4; ++n) {
            int dcol = n*16 + lr;
            sh8 v0 = Vs8[buf][dcol*8 + (lg       ^ (dcol & 7))];
            sh8 v1 = Vs8[buf][dcol*8 + ((4 + lg) ^ (dcol & 7))];
            accO[n] = mfma16(pa[1], v1, mfma16(pa[0], v0, accO[n]));
        }

        asm volatile("s_waitcnt lgkmcnt(0)" ::: "memory");
    }
    #undef ASTAGE
    #undef RMLOAD

    l_lane += __shfl_xor(l_lane, 16);
    l_lane += __shfl_xor(l_lane, 32);

    short* Op = (ks < 2) ? OpA : OpB;
    #pragma unroll
    for (int r = 0; r < 4; ++r) {
        size_t row = (size_t)((ks & 1)*MTOK + qrow0 + lg*4 + r);
        #pragma unroll
        for (int n = 0; n < 4; ++n)
            Op[row*512 + h*64 + n*16 + lr] = f2bf(accO[n][r]);
    }
    if (lg == 0) {
        size_t mrow = (size_t)(ks*MTOK + qrow0 + lr);
        ml[(mrow*NHEADS + h)*2 + 0] = m_i;
        ml[(mrow*NHEADS + h)*2 + 1] = l_lane;
    }
}

// ---------------- combine 4 KV-split partials -> bf16 O ----------------
__global__ __launch_bounds__(256) void attn_combine4(const short* __restrict__ OpA,
    const short* __restrict__ OpB, const float* __restrict__ ml,
    short* __restrict__ ob)
{
    int idx = blockIdx.x*256 + threadIdx.x;     // MTOK*128 threads
    int tok = idx >> 7, dd = (idx & 127) * 4;
    int h = dd >> 6;
    float m[4], l[4];
    #pragma unroll
    for (int s = 0; s < 4; ++s) {
        m[s] = ml[(((size_t)s*MTOK + tok)*NHEADS + h)*2 + 0];
        l[s] = ml[(((size_t)s*MTOK + tok)*NHEADS + h)*2 + 1];
    }
    float mm = fmaxf(fmaxf(m[0], m[1]), fmaxf(m[2], m[3]));
    float wsum = 0.f, a0 = 0.f, a1 = 0.f, a2 = 0.f, a3 = 0.f;
    #pragma unroll
    for (int s = 0; s < 4; ++s) {
        float wv = ex2(m[s] - mm);
        wsum += wv * l[s];
        const short* Op = (s < 2) ? OpA : OpB;
        short4 p = *reinterpret_cast<const short4*>(&Op[((size_t)((s&1)*MTOK) + tok)*512 + dd]);
        a0 += bf2f(p.x)*wv; a1 += bf2f(p.y)*wv;
        a2 += bf2f(p.z)*wv; a3 += bf2f(p.w)*wv;
    }
    float inv = 1.f / wsum;
    short4 o;
    o.x = f2bf(a0*inv); o.y = f2bf(a1*inv);
    o.z = f2bf(a2*inv); o.w = f2bf(a3*inv);
    *reinterpret_cast<short4*>(&ob[(size_t)tok*512 + dd]) = o;
}

// -------------------------------------------------------------------------------
extern "C" void kernel_launch(void* const* d_in, const int* in_sizes, int n_in,
                              void* d_out, int out_size, void* d_ws, size_t ws_size,
                              hipStream_t stream)
{
    const float* x      = (const float*)d_in[0];
    const float* coords = (const float*)d_in[1];
    const unsigned char* mask = (const unsigned char*)d_in[2];
    const float* ln1_g = (const float*)d_in[3];
    const float* ln1_b = (const float*)d_in[4];
    const float* w_qkv = (const float*)d_in[5];
    const float* b_qkv = (const float*)d_in[6];
    const float* w_edge= (const float*)d_in[7];
    const float* w_out = (const float*)d_in[8];
    const float* b_out = (const float*)d_in[9];
    const float* ln2_g = (const float*)d_in[10];
    const float* ln2_b = (const float*)d_in[11];
    const float* w1    = (const float*)d_in[12];
    const float* b1    = (const float*)d_in[13];
    const float* w2    = (const float*)d_in[14];
    const float* b2    = (const float*)d_in[15];
    float* out = (float*)d_out;

    char* W = (char*)d_ws;
    const size_t MB = 1024*1024;
    float* x1    = (float*)(W);                    // [0,4M) f32 (written by outproj)
    short* qk    = (short*)(W + 4*MB);             // [4M,8M)
    short* vtb   = (short*)(W + 8*MB);             // [8M,10M)
    short* woutT = (short*)(W + 10*MB);            // [10M,10.5M)
    short* xln   = (short*)(W + 10*MB + 512*1024); // [10.5M,12.5M)  (later y)
    short* wqkvT = (short*)(W + 12*MB + 512*1024); // [12.5M,14M)
    short* OpB   = (short*)(W + 10*MB + 512*1024); // [10.5M,14.5M) over dead xln/wqkvT
    short* OpA   = (short*)(W + 14*MB + 512*1024); // [14.5M,18.5M)
    short* rnT   = (short*)(W + 18*MB + 512*1024); // [18.5M,22.5M) bf16 2048x1024
    float* mlp   = (float*)(W + 22*MB + 512*1024); // [22.5M,23M) 4x2048x8x2 f32
    unsigned long long* mb64 = (unsigned long long*)(W + 23*MB); // [23M,23.25M)
    short* ob    = (short*)(W + 6*MB);             // [6M,8M)  (qk dead after attn)
    short* y     = xln;                            // [10.5M,12.5M) (OpB dead)
    short* w1T   = (short*)(W + 4*MB);             // [4M,6M)  (qk dead)
    short* w2T   = (short*)(W + 8*MB);             // [8M,10M) (vtb dead)
    short* hid   = (short*)(W + 14*MB + 512*1024); // [14.5M,22.5M) (OpA/rnT dead)

    // ---- phase 1 ----
    prep<<<dim3(2048,1,1), 256, 0, stream>>>(coords, mask, rnT, mb64);
    wconv2x<<<dim3(1024,1,1), 256, 0, stream>>>(w_qkv, wqkvT, 512, 1536, 768,
                                                w_out, woutT, 512, 512);
    ln_bf16<false><<<MTOK, 256, 0, stream>>>(x, ln1_g, ln1_b, xln, nullptr, nullptr);
    gemm64<0,true,false,1,true,8><<<dim3(512,1,1), 256, 0, stream>>>(
        xln, wqkvT, b_qkv, nullptr, qk, MTOK, 1024, 512, 16);
    gemm64<0,true,true,1,false,8><<<dim3(256,1,1), 256, 0, stream>>>(
        wqkvT + (size_t)1024*512, xln, b_qkv + 1024, nullptr, vtb, 512, MTOK, 512, 32);
    attn_reg<<<dim3(1024,1,1), 256, 0, stream>>>(qk, vtb, rnT, mb64, w_edge, OpA, OpB, mlp);
    attn_combine4<<<dim3(1024,1,1), 256, 0, stream>>>(OpA, OpB, mlp, ob);
    // x1 = ob @ w_out + b_out + x   (no split-K, no atomics)
    gemm64<1,false,false,1,false,8><<<dim3(256,1,1), 256, 0, stream>>>(
        ob, woutT, b_out, x, x1, MTOK, 512, 512, 8);
    // ---- phase 2 ----
    wconv2x<<<dim3(2048,1,1), 256, 0, stream>>>(w1, w1T, 512, 2048, 1024,
                                                w2, w2T, 2048, 512);
    ln_bf16<true><<<MTOK, 256, 0, stream>>>(x1, ln2_g, ln2_b, y, b2, out);
    gemm64<2,true,false,1,false,8><<<dim3(1024,1,1), 256, 0, stream>>>(
        y, w1T, b1, nullptr, hid, MTOK, 2048, 512, 32);
    // out += hid @ w2   (split-K=2 atomics, halved from 4)
    gemm64<3,false,false,2,false,16><<<dim3(256,1,2), 256, 0, stream>>>(
        hid, w2T, nullptr, nullptr, out, MTOK, 512, 2048, 8);
}